// Round 1
// baseline (593.388 us; speedup 1.0000x reference)
//
#include <hip/hip_runtime.h>

// XCA: cross-covariance attention, B=32 N=3136 D=384 H=8 C=48.
// Round 3: BK=64 GEMMs (two [128][32] sub-tiles, half the barriers),
// bijective XCD-chunked block swizzle on both big GEMMs, attn_s staged via
// global_load_lds with sumsq computed as MFMA diag (mfma(a,a)), softmax
// emits bf16 padded [48][64] consumed directly by attn_v.

typedef __bf16 bf16x8 __attribute__((ext_vector_type(8)));
typedef float floatx4 __attribute__((ext_vector_type(4)));
typedef unsigned short u16;

#define B_ 32
#define N_ 3136
#define D_ 384
#define H_ 8
#define C_ 48
#define E3_ 1152
#define BN_ 100352   // B_*N_

__device__ __forceinline__ u16 f2b(float f) {
  unsigned u = __builtin_bit_cast(unsigned, f);
  u += 0x7FFFu + ((u >> 16) & 1u);   // RNE
  return (u16)(u >> 16);
}
__device__ __forceinline__ void gload16(const u16* g, u16* l) {
  __builtin_amdgcn_global_load_lds(
      (const __attribute__((address_space(1))) void*)g,
      (__attribute__((address_space(3))) void*)l, 16, 0, 0);
}

// ---------------- fp32 -> bf16 convert ----------------
__global__ __launch_bounds__(256) void k_cvt(const float* __restrict__ in,
                                             u16* __restrict__ out, int n4) {
  int i = blockIdx.x * 256 + threadIdx.x;
  if (i < n4) {
    float4 v = ((const float4*)in)[i];
    ushort4 o;
    o.x = f2b(v.x); o.y = f2b(v.y); o.z = f2b(v.z); o.w = f2b(v.w);
    ((ushort4*)out)[i] = o;
  }
}

// ---------------- GEMM1: O[e][g] = sum_d W[e][d] X[g][d], bf16 out ----------
// 128x128 tile, BK=64 as two [128][32] sub-tiles (same bank profile as BK=32,
// half the barrier pairs). XCD-chunked swizzle: 7056 blocks = 8 XCDs x 882,
// so the 9 e-blocks sharing an X g-tile land on ONE XCD's L2.
__global__ __launch_bounds__(256) void k_gemm_qkv(const u16* __restrict__ W,
                                                  const u16* __restrict__ X,
                                                  u16* __restrict__ O) {
  const int K = D_;
  int lin = blockIdx.y * 9 + blockIdx.x;          // hw linear id (x fastest)
  int w = (lin & 7) * 882 + (lin >> 3);           // XCD c -> w in [882c,882c+882)
  int m0 = (w % 9) * 128;                         // e-tile (fastest within chunk)
  int n0 = (w / 9) * 128;                         // g-tile
  __shared__ u16 As[2][128][32];
  __shared__ u16 Bs[2][128][32];
  int t = threadIdx.x, wid = t >> 6, lane = t & 63;
  int srow = wid * 32 + (lane >> 2);              // staging row; +16 for 2nd call
  int scol = (lane & 3) * 8;
  int wm = (wid & 1) * 64, wn = (wid >> 1) * 64;
  int r = lane & 15, quad = lane >> 4, q8 = quad * 8;

  const u16* gA = W + (size_t)(m0 + srow) * K + scol;
  const u16* gB = X + (size_t)(n0 + srow) * K + scol;

  floatx4 acc[4][4] = {};
  for (int k0 = 0; k0 < K; k0 += 64) {
#pragma unroll
    for (int ks = 0; ks < 2; ks++) {
      gload16(gA + k0 + ks * 32,          &As[ks][wid * 32][0]);
      gload16(gA + k0 + ks * 32 + 16 * K, &As[ks][wid * 32 + 16][0]);
      gload16(gB + k0 + ks * 32,          &Bs[ks][wid * 32][0]);
      gload16(gB + k0 + ks * 32 + 16 * K, &Bs[ks][wid * 32 + 16][0]);
    }
    __syncthreads();
#pragma unroll
    for (int ks = 0; ks < 2; ks++) {
      bf16x8 af[4], bf[4];
#pragma unroll
      for (int i = 0; i < 4; i++) af[i] = *(const bf16x8*)(&As[ks][wm + i * 16 + r][q8]);
#pragma unroll
      for (int j = 0; j < 4; j++) bf[j] = *(const bf16x8*)(&Bs[ks][wn + j * 16 + r][q8]);
#pragma unroll
      for (int i = 0; i < 4; i++)
#pragma unroll
        for (int j = 0; j < 4; j++)
          acc[i][j] = __builtin_amdgcn_mfma_f32_16x16x32_bf16(af[i], bf[j], acc[i][j], 0, 0, 0);
    }
    __syncthreads();
  }
#pragma unroll
  for (int i = 0; i < 4; i++)
#pragma unroll
    for (int j = 0; j < 4; j++)
#pragma unroll
      for (int v = 0; v < 4; v++) {
        int rr = m0 + wm + i * 16 + quad * 4 + v;
        int cc = n0 + wn + j * 16 + r;
        O[(size_t)rr * BN_ + cc] = f2b(acc[i][j][v]);
      }
}

// ---------------- attn_s: split-K, sumsq via MFMA diag ----------------------
// S[bh][c][d] += Q_bh[c][ns..ns+448) . K_bh[d][..]^T
// sumsq(Q row) = diag(Q.Q^T): one extra mfma(a,a) per fragment — no per-elem
// VALU, so staging uses global_load_lds (rows 48..63 = in-bounds garbage,
// discarded by the rr/cc<48 guards).
__global__ __launch_bounds__(256) void k_attn_s(const u16* __restrict__ QKV,
                                                float* __restrict__ S,
                                                float* __restrict__ ssq) {
  int bh = blockIdx.x, b = bh >> 3, h = bh & 7;
  int ns = blockIdx.y * 448;
  const u16* Qb = QKV + (size_t)(h * C_) * BN_ + b * N_ + ns;
  const u16* Kb = QKV + (size_t)(D_ + h * C_) * BN_ + b * N_ + ns;
  __shared__ u16 As[64][32];
  __shared__ u16 Bs[64][32];
  int t = threadIdx.x, wid = t >> 6, lane = t & 63;
  int wm = (wid & 1) * 32, wn = (wid >> 1) * 32;
  int r = lane & 15, quad = lane >> 4, q8 = quad * 8;
  int srow = wid * 16 + (lane >> 2);
  int scol = (lane & 3) * 8;
  const u16* gQ = Qb + (size_t)srow * BN_ + scol;
  const u16* gK = Kb + (size_t)srow * BN_ + scol;
  u16* lQ = &As[wid * 16][0];
  u16* lK = &Bs[wid * 16][0];

  floatx4 acc[2][2] = {};
  floatx4 dq0 = {}, dq1 = {}, dk0 = {}, dk1 = {};
  for (int k0 = 0; k0 < 448; k0 += 32) {
    gload16(gQ + k0, lQ);
    gload16(gK + k0, lK);
    __syncthreads();
    bf16x8 a0 = *(const bf16x8*)(&As[wm + r][q8]);
    bf16x8 a1 = *(const bf16x8*)(&As[wm + 16 + r][q8]);
    bf16x8 b0 = *(const bf16x8*)(&Bs[wn + r][q8]);
    bf16x8 b1 = *(const bf16x8*)(&Bs[wn + 16 + r][q8]);
    acc[0][0] = __builtin_amdgcn_mfma_f32_16x16x32_bf16(a0, b0, acc[0][0], 0, 0, 0);
    acc[0][1] = __builtin_amdgcn_mfma_f32_16x16x32_bf16(a0, b1, acc[0][1], 0, 0, 0);
    acc[1][0] = __builtin_amdgcn_mfma_f32_16x16x32_bf16(a1, b0, acc[1][0], 0, 0, 0);
    acc[1][1] = __builtin_amdgcn_mfma_f32_16x16x32_bf16(a1, b1, acc[1][1], 0, 0, 0);
    // sumsq diag: Q rows 0-15,16-31 (wave0), 32-47 (wave1);
    //             K rows 0-15,16-31 (wave0), 32-47 (wave2)
    if (wid == 0) {
      dq0 = __builtin_amdgcn_mfma_f32_16x16x32_bf16(a0, a0, dq0, 0, 0, 0);
      dq1 = __builtin_amdgcn_mfma_f32_16x16x32_bf16(a1, a1, dq1, 0, 0, 0);
      dk0 = __builtin_amdgcn_mfma_f32_16x16x32_bf16(b0, b0, dk0, 0, 0, 0);
      dk1 = __builtin_amdgcn_mfma_f32_16x16x32_bf16(b1, b1, dk1, 0, 0, 0);
    } else if (wid == 1) {
      dq0 = __builtin_amdgcn_mfma_f32_16x16x32_bf16(a0, a0, dq0, 0, 0, 0);
    } else if (wid == 2) {
      dk0 = __builtin_amdgcn_mfma_f32_16x16x32_bf16(b0, b0, dk0, 0, 0, 0);
    }
    __syncthreads();
  }
  // diag elements live on lanes where col(r) == row(quad*4+v)
#pragma unroll
  for (int v = 0; v < 4; v++) {
    if (r == quad * 4 + v) {
      int dr = quad * 4 + v;
      if (wid == 0) {
        atomicAdd(&ssq[bh * 48 + dr],              dq0[v]);
        atomicAdd(&ssq[bh * 48 + 16 + dr],         dq1[v]);
        atomicAdd(&ssq[12288 + bh * 48 + dr],      dk0[v]);
        atomicAdd(&ssq[12288 + bh * 48 + 16 + dr], dk1[v]);
      } else if (wid == 1) {
        atomicAdd(&ssq[bh * 48 + 32 + dr], dq0[v]);
      } else if (wid == 2) {
        atomicAdd(&ssq[12288 + bh * 48 + 32 + dr], dk0[v]);
      }
    }
  }
#pragma unroll
  for (int mt = 0; mt < 2; mt++)
#pragma unroll
    for (int nt = 0; nt < 2; nt++)
#pragma unroll
      for (int v = 0; v < 4; v++) {
        int rr = wm + mt * 16 + quad * 4 + v;
        int cc = wn + nt * 16 + r;
        if (rr < 48 && cc < 48)
          atomicAdd(&S[(size_t)bh * 2304 + rr * 48 + cc], acc[mt][nt][v]);
      }
}

// ---------------- softmax over d, emits bf16 [bh][48][64] (d padded) --------
__global__ __launch_bounds__(64) void k_softmax(const float* __restrict__ S,
                                                const float* __restrict__ ssq,
                                                const float* __restrict__ temp,
                                                u16* __restrict__ attnb) {
  int bh = blockIdx.x, h = bh & 7;
  int c = threadIdx.x;
  if (c >= 48) return;
  float sq = 1.f / fmaxf(sqrtf(ssq[bh * 48 + c]), 1e-12f);
  float T = temp[h];
  const float* Srow = S + (size_t)bh * 2304 + c * 48;
  float v[48];
  float mx = -1e30f;
#pragma unroll
  for (int d = 0; d < 48; d++) {
    float sk = 1.f / fmaxf(sqrtf(ssq[12288 + bh * 48 + d]), 1e-12f);
    float l = Srow[d] * sq * sk * T;
    v[d] = l;
    mx = fmaxf(mx, l);
  }
  float sum = 0.f;
#pragma unroll
  for (int d = 0; d < 48; d++) { v[d] = expf(v[d] - mx); sum += v[d]; }
  float inv = 1.f / sum;
  u16* Arow = attnb + (size_t)bh * 3072 + c * 64;
#pragma unroll
  for (int d = 0; d < 48; d++) Arow[d] = f2b(v[d] * inv);
#pragma unroll
  for (int d = 48; d < 64; d++) Arow[d] = 0;
}

// ---------------- outT[g][h*48+c] = sum_d attn[c][d] V[d][n] ---------------
// grid: x = n-tiles(49), y = bh(256). MFMA: M=n(64), N=c(48), K=d(48 pad 64).
__global__ __launch_bounds__(256) void k_attn_v(const u16* __restrict__ QKV,
                                                const u16* __restrict__ attnb,
                                                u16* __restrict__ outT) {
  int bh = blockIdx.y, b = bh >> 3, h = bh & 7;
  int n0 = blockIdx.x * 64;
  const u16* V = QKV + (size_t)(2 * D_ + h * C_) * BN_ + b * N_;
  __shared__ u16 Vt[64][64];   // [n_local][d], zero-padded d 48..63
  __shared__ u16 Aw[48][64];   // attn [c][d] bf16, pre-padded by k_softmax
  int t = threadIdx.x;
  for (int i = t; i < 512; i += 256) ((int4*)Vt)[i] = int4{0, 0, 0, 0};
  {
    const int4* src = (const int4*)(attnb + (size_t)bh * 3072);
    for (int i = t; i < 384; i += 256) ((int4*)Aw)[i] = src[i];
  }
  __syncthreads();
  for (int idx = t; idx < 768; idx += 256) {
    int d = idx >> 4, c4 = (idx & 15) * 4;
    ushort4 v = *(const ushort4*)(V + (size_t)d * BN_ + n0 + c4);
    Vt[c4 + 0][d] = v.x; Vt[c4 + 1][d] = v.y;
    Vt[c4 + 2][d] = v.z; Vt[c4 + 3][d] = v.w;
  }
  __syncthreads();
  int wid = t >> 6, lane = t & 63;
  int r = lane & 15, quad = lane >> 4, q8 = quad * 8;
  floatx4 acc[3] = {};
#pragma unroll
  for (int ks = 0; ks < 2; ks++) {
    bf16x8 a = *(const bf16x8*)(&Vt[wid * 16 + r][ks * 32 + q8]);
#pragma unroll
    for (int nt = 0; nt < 3; nt++) {
      bf16x8 bb = *(const bf16x8*)(&Aw[nt * 16 + r][ks * 32 + q8]);
      acc[nt] = __builtin_amdgcn_mfma_f32_16x16x32_bf16(a, bb, acc[nt], 0, 0, 0);
    }
  }
  u16* Ob = outT + (size_t)(b * N_) * D_;
#pragma unroll
  for (int nt = 0; nt < 3; nt++)
#pragma unroll
    for (int j = 0; j < 4; j++) {
      int n = n0 + wid * 16 + quad * 4 + j;
      int e = h * C_ + nt * 16 + r;
      Ob[(size_t)n * D_ + e] = f2b(acc[nt][j]);
    }
}

// ---------------- proj: Y[g][f] = sum_e OT[g][e] P[f][e] + bias[f] ---------
// BK=64 structure; XCD-chunked swizzle: 2352 = 8 x 294.
__global__ __launch_bounds__(256) void k_gemm_proj(const u16* __restrict__ OT,
                                                   const u16* __restrict__ P,
                                                   const float* __restrict__ bias,
                                                   float* __restrict__ Y) {
  const int K = D_;
  int lin = blockIdx.y * 3 + blockIdx.x;
  int w = (lin & 7) * 294 + (lin >> 3);
  int n0 = (w % 3) * 128;                         // f-tile
  int m0 = (w / 3) * 128;                         // g-tile
  __shared__ u16 As[2][128][32];
  __shared__ u16 Bs[2][128][32];
  int t = threadIdx.x, wid = t >> 6, lane = t & 63;
  int srow = wid * 32 + (lane >> 2);
  int scol = (lane & 3) * 8;
  int wm = (wid & 1) * 64, wn = (wid >> 1) * 64;
  int r = lane & 15, quad = lane >> 4, q8 = quad * 8;

  const u16* gA = OT + (size_t)(m0 + srow) * K + scol;
  const u16* gB = P + (size_t)(n0 + srow) * K + scol;

  floatx4 acc[4][4] = {};
  for (int k0 = 0; k0 < K; k0 += 64) {
#pragma unroll
    for (int ks = 0; ks < 2; ks++) {
      gload16(gA + k0 + ks * 32,          &As[ks][wid * 32][0]);
      gload16(gA + k0 + ks * 32 + 16 * K, &As[ks][wid * 32 + 16][0]);
      gload16(gB + k0 + ks * 32,          &Bs[ks][wid * 32][0]);
      gload16(gB + k0 + ks * 32 + 16 * K, &Bs[ks][wid * 32 + 16][0]);
    }
    __syncthreads();
#pragma unroll
    for (int ks = 0; ks < 2; ks++) {
      bf16x8 af[4], bf[4];
#pragma unroll
      for (int i = 0; i < 4; i++) af[i] = *(const bf16x8*)(&As[ks][wm + i * 16 + r][q8]);
#pragma unroll
      for (int j = 0; j < 4; j++) bf[j] = *(const bf16x8*)(&Bs[ks][wn + j * 16 + r][q8]);
#pragma unroll
      for (int i = 0; i < 4; i++)
#pragma unroll
        for (int j = 0; j < 4; j++)
          acc[i][j] = __builtin_amdgcn_mfma_f32_16x16x32_bf16(af[i], bf[j], acc[i][j], 0, 0, 0);
    }
    __syncthreads();
  }
#pragma unroll
  for (int i = 0; i < 4; i++)
#pragma unroll
    for (int j = 0; j < 4; j++) {
      int cc = n0 + wn + j * 16 + r;
      float bv = bias[cc];
#pragma unroll
      for (int v = 0; v < 4; v++) {
        int rr = m0 + wm + i * 16 + quad * 4 + v;
        Y[(size_t)rr * D_ + cc] = acc[i][j][v] + bv;
      }
    }
}

extern "C" void kernel_launch(void* const* d_in, const int* in_sizes, int n_in,
                              void* d_out, int out_size, void* d_ws, size_t ws_size,
                              hipStream_t stream) {
  const float* x      = (const float*)d_in[0];   // 32*3136*384
  const float* qkv_w  = (const float*)d_in[1];   // 1152*384
  const float* temp   = (const float*)d_in[2];   // 8
  const float* proj_w = (const float*)d_in[3];   // 384*384
  const float* proj_b = (const float*)d_in[4];   // 384
  float* out = (float*)d_out;

  // workspace layout (bytes)
  char* ws = (char*)d_ws;
  u16*   qkv    = (u16*)(ws);                    // 231,211,008  [e][g] bf16
  u16*   xbf    = (u16*)(ws + 231211008);        //  77,070,336  (aliased by outT)
  u16*   wbf    = (u16*)(ws + 308281344);        //     884,736
  u16*   pwbf   = (u16*)(ws + 309166080);        //     294,912
  float* S      = (float*)(ws + 309460992);      //   2,359,296  [bh][48][48]
  float* ssq    = (float*)(ws + 311820288);      //      98,304  [2][256][48]
  u16*   attnb  = (u16*)(ws + 311918592);        //   1,572,864  [bh][48][64] bf16
  u16*   outT   = xbf;  // x_bf16 dead after gemm_qkv; reuse for outT [g][e]

  hipMemsetAsync(S, 0, 2359296 + 98304, stream);  // zero S + ssq (adjacent)

  k_cvt<<<38535168 / 4 / 256, 256, 0, stream>>>(x, xbf, 38535168 / 4);
  k_cvt<<<442368 / 4 / 256, 256, 0, stream>>>(qkv_w, wbf, 442368 / 4);
  k_cvt<<<147456 / 4 / 256, 256, 0, stream>>>(proj_w, pwbf, 147456 / 4);

  k_gemm_qkv<<<dim3(9, 784), 256, 0, stream>>>(wbf, xbf, qkv);
  k_attn_s<<<dim3(256, 7), 256, 0, stream>>>(qkv, S, ssq);
  k_softmax<<<256, 64, 0, stream>>>(S, ssq, temp, attnb);
  k_attn_v<<<dim3(49, 256), 256, 0, stream>>>(qkv, attnb, outT);
  k_gemm_proj<<<dim3(3, 784), 256, 0, stream>>>(outT, pwbf, proj_b, out);
}

// Round 3
// 557.591 us; speedup vs baseline: 1.0642x; 1.0642x over previous
//
#include <hip/hip_runtime.h>

// XCA: cross-covariance attention, B=32 N=3136 D=384 H=8 C=48.
// Round 5: Gram-factored algorithm (round-4 structure) with the k_mid2
// staging bug fixed: Wq/Wk slots now copy 8 u16 (int4), not 4 — half of
// each W tile was previously stale LDS garbage.
//   G_b = X_b^T X_b ; S_bh = Wq_h G_b Wk_h^T ; ssq = diag(W G W^T)
//   A = softmax ; M = A Wv ; R_b = P M_b ; Y_b = X_b R_b^T + bias

typedef __bf16 bf16x8 __attribute__((ext_vector_type(8)));
typedef float floatx4 __attribute__((ext_vector_type(4)));
typedef unsigned short u16;

#define B_ 32
#define N_ 3136
#define D_ 384
#define H_ 8
#define C_ 48
#define BN_ 100352   // B_*N_

__device__ __forceinline__ u16 f2b(float f) {
  unsigned u = __builtin_bit_cast(unsigned, f);
  u += 0x7FFFu + ((u >> 16) & 1u);   // RNE
  return (u16)(u >> 16);
}
__device__ __forceinline__ void gload16(const u16* g, u16* l) {
  __builtin_amdgcn_global_load_lds(
      (const __attribute__((address_space(1))) void*)g,
      (__attribute__((address_space(3))) void*)l, 16, 0, 0);
}

// ---------------- fp32 -> bf16 convert ----------------
__global__ __launch_bounds__(256) void k_cvt(const float* __restrict__ in,
                                             u16* __restrict__ out, int n4) {
  int i = blockIdx.x * 256 + threadIdx.x;
  if (i < n4) {
    float4 v = ((const float4*)in)[i];
    ushort4 o;
    o.x = f2b(v.x); o.y = f2b(v.y); o.z = f2b(v.z); o.w = f2b(v.w);
    ((ushort4*)out)[i] = o;
  }
}

// ---------------- cvt + transpose: x -> xbf [g][d] and xT [d][g] ------------
// grid (6 d-tiles, 49 n-tiles, 32 b), 64x64 tiles.
__global__ __launch_bounds__(256) void k_cvt_t(const float* __restrict__ x,
                                               u16* __restrict__ xbf,
                                               u16* __restrict__ xT) {
  int d0 = blockIdx.x * 64, n0 = blockIdx.y * 64, b = blockIdx.z;
  const float* xp = x + ((size_t)b * N_ + n0) * D_ + d0;
  __shared__ u16 L[64][68];
  int t = threadIdx.x;
  int nl = t >> 4, dl = (t & 15) * 4;
#pragma unroll
  for (int p = 0; p < 4; p++) {
    int n = nl + p * 16;
    float4 v = *(const float4*)(xp + (size_t)n * D_ + dl);
    ushort4 o;
    o.x = f2b(v.x); o.y = f2b(v.y); o.z = f2b(v.z); o.w = f2b(v.w);
    *(ushort4*)(xbf + ((size_t)(b * N_ + n0 + n)) * D_ + d0 + dl) = o;
    *(ushort4*)(&L[n][dl]) = o;
  }
  __syncthreads();
  int dl2 = t >> 4, nl2 = (t & 15) * 4;
#pragma unroll
  for (int p = 0; p < 4; p++) {
    int d = dl2 + p * 16;
    ushort4 o;
    o.x = L[nl2 + 0][d]; o.y = L[nl2 + 1][d];
    o.z = L[nl2 + 2][d]; o.w = L[nl2 + 3][d];
    *(ushort4*)(xT + (size_t)(d0 + d) * BN_ + b * N_ + n0 + nl2) = o;
  }
}

// ---------------- WvT[h][j][d] = qkv_w[768+h*48+d][j], d-padded to 64 -------
__global__ __launch_bounds__(256) void k_wvt(const float* __restrict__ qkv_w,
                                             u16* __restrict__ wvT) {
  int h = blockIdx.x, t = threadIdx.x;
  for (int idx = t; idx < 384 * 64; idx += 256) {
    int j = idx >> 6, d = idx & 63;
    float v = (d < 48) ? qkv_w[(size_t)(2 * D_ + h * C_ + d) * D_ + j] : 0.f;
    wvT[(size_t)h * 24576 + idx] = f2b(v);
  }
}

// ---------------- gram: G[b] += xT[m-rows] . xT[n-rows]^T over n-split ------
// grid (9 tiles, 32 b, 7 splits). 128x128 tile, K=448, BK=64, f32 atomics.
__global__ __launch_bounds__(256) void k_gram(const u16* __restrict__ xT,
                                              float* __restrict__ G) {
  int tile = blockIdx.x, b = blockIdx.y, ns = blockIdx.z * 448;
  int m0 = (tile % 3) * 128, n0 = (tile / 3) * 128;
  __shared__ u16 As[2][128][32];
  __shared__ u16 Bs[2][128][32];
  int t = threadIdx.x, wid = t >> 6, lane = t & 63;
  int srow = wid * 32 + (lane >> 2), scol = (lane & 3) * 8;
  int wm = (wid & 1) * 64, wn = (wid >> 1) * 64;
  int r = lane & 15, quad = lane >> 4, q8 = quad * 8;
  const u16* base = xT + (size_t)b * N_ + ns + scol;
  const u16* gA = base + (size_t)(m0 + srow) * BN_;
  const u16* gB = base + (size_t)(n0 + srow) * BN_;

  floatx4 acc[4][4] = {};
  for (int k0 = 0; k0 < 448; k0 += 64) {
#pragma unroll
    for (int ks = 0; ks < 2; ks++) {
      gload16(gA + k0 + ks * 32,                     &As[ks][wid * 32][0]);
      gload16(gA + k0 + ks * 32 + (size_t)16 * BN_,  &As[ks][wid * 32 + 16][0]);
      gload16(gB + k0 + ks * 32,                     &Bs[ks][wid * 32][0]);
      gload16(gB + k0 + ks * 32 + (size_t)16 * BN_,  &Bs[ks][wid * 32 + 16][0]);
    }
    __syncthreads();
#pragma unroll
    for (int ks = 0; ks < 2; ks++) {
      bf16x8 af[4], bf[4];
#pragma unroll
      for (int i = 0; i < 4; i++) af[i] = *(const bf16x8*)(&As[ks][wm + i * 16 + r][q8]);
#pragma unroll
      for (int j = 0; j < 4; j++) bf[j] = *(const bf16x8*)(&Bs[ks][wn + j * 16 + r][q8]);
#pragma unroll
      for (int i = 0; i < 4; i++)
#pragma unroll
        for (int j = 0; j < 4; j++)
          acc[i][j] = __builtin_amdgcn_mfma_f32_16x16x32_bf16(af[i], bf[j], acc[i][j], 0, 0, 0);
    }
    __syncthreads();
  }
  float* Gb = G + (size_t)b * 147456;
#pragma unroll
  for (int i = 0; i < 4; i++)
#pragma unroll
    for (int j = 0; j < 4; j++)
#pragma unroll
      for (int v = 0; v < 4; v++) {
        int rr = m0 + wm + i * 16 + quad * 4 + v;
        int cc = n0 + wn + j * 16 + r;
        atomicAdd(&Gb[(size_t)rr * 384 + cc], acc[i][j][v]);
      }
}

// ---------------- mid1: U[b][e][j] = sum_i Wqk[e][i] G[b][j][i] (G sym) -----
// grid (6 e-tiles, 3 j-tiles, 32 b). Output f32.
__global__ __launch_bounds__(256) void k_mid1(const u16* __restrict__ wbf,
                                              const u16* __restrict__ Gb,
                                              float* __restrict__ U) {
  int m0 = blockIdx.x * 128, n0 = blockIdx.y * 128, b = blockIdx.z;
  __shared__ u16 As[2][128][32];
  __shared__ u16 Bs[2][128][32];
  int t = threadIdx.x, wid = t >> 6, lane = t & 63;
  int srow = wid * 32 + (lane >> 2), scol = (lane & 3) * 8;
  int wm = (wid & 1) * 64, wn = (wid >> 1) * 64;
  int r = lane & 15, quad = lane >> 4, q8 = quad * 8;
  const u16* gA = wbf + (size_t)(m0 + srow) * 384 + scol;
  const u16* gB = Gb + (size_t)b * 147456 + (size_t)(n0 + srow) * 384 + scol;

  floatx4 acc[4][4] = {};
  for (int k0 = 0; k0 < 384; k0 += 64) {
#pragma unroll
    for (int ks = 0; ks < 2; ks++) {
      gload16(gA + k0 + ks * 32,            &As[ks][wid * 32][0]);
      gload16(gA + k0 + ks * 32 + 16 * 384, &As[ks][wid * 32 + 16][0]);
      gload16(gB + k0 + ks * 32,            &Bs[ks][wid * 32][0]);
      gload16(gB + k0 + ks * 32 + 16 * 384, &Bs[ks][wid * 32 + 16][0]);
    }
    __syncthreads();
#pragma unroll
    for (int ks = 0; ks < 2; ks++) {
      bf16x8 af[4], bf[4];
#pragma unroll
      for (int i = 0; i < 4; i++) af[i] = *(const bf16x8*)(&As[ks][wm + i * 16 + r][q8]);
#pragma unroll
      for (int j = 0; j < 4; j++) bf[j] = *(const bf16x8*)(&Bs[ks][wn + j * 16 + r][q8]);
#pragma unroll
      for (int i = 0; i < 4; i++)
#pragma unroll
        for (int j = 0; j < 4; j++)
          acc[i][j] = __builtin_amdgcn_mfma_f32_16x16x32_bf16(af[i], bf[j], acc[i][j], 0, 0, 0);
    }
    __syncthreads();
  }
  float* Ub = U + (size_t)b * 294912;
#pragma unroll
  for (int i = 0; i < 4; i++)
#pragma unroll
    for (int j = 0; j < 4; j++)
#pragma unroll
      for (int v = 0; v < 4; v++) {
        int rr = m0 + wm + i * 16 + quad * 4 + v;
        int cc = n0 + wn + j * 16 + r;
        Ub[(size_t)rr * 384 + cc] = acc[i][j][v];
      }
}

// ---------------- mid2: per bh: S, ssq (MFMA diag), softmax, M = A Wv -------
// Writes MT[b][j][e] bf16 (transposed M for mid3's B-operand).
__global__ __launch_bounds__(256) void k_mid2(const float* __restrict__ U,
                                              const u16* __restrict__ wbf,
                                              const u16* __restrict__ wvT,
                                              const float* __restrict__ temp,
                                              u16* __restrict__ MT) {
  int bh = blockIdx.x, b = bh >> 3, h = bh & 7;
  __shared__ __align__(16) u16 sUq[48][32], sUk[48][32], sWq[48][32], sWk[48][32];
  __shared__ __align__(16) u16 sA[48][72];
  __shared__ float sSsq[96];
  __shared__ float sInv[96];
  int t = threadIdx.x, wid = t >> 6, lane = t & 63;
  int r = lane & 15, quad = lane >> 4, q8 = quad * 8;
  const float* Uq = U + (size_t)b * 294912 + (size_t)(h * C_) * 384;
  const float* Uk = U + (size_t)b * 294912 + (size_t)(D_ + h * C_) * 384;
  const u16* Wq = wbf + (size_t)(h * C_) * 384;
  const u16* Wk = wbf + (size_t)(D_ + h * C_) * 384;

  floatx4 accS[3] = {};
  floatx4 accD[6] = {};
  for (int k0 = 0; k0 < 384; k0 += 32) {
    for (int idx = t; idx < 768; idx += 256) {
      int tile = idx / 192, rem = idx - tile * 192;
      int rr = rem >> 2, c8 = (rem & 3) * 8;
      if (tile < 2) {
        const float* src = (tile == 0 ? Uq : Uk) + (size_t)rr * 384 + k0 + c8;
        float4 a = *(const float4*)src;
        float4 bb = *(const float4*)(src + 4);
        ushort4 lo, hi;
        lo.x = f2b(a.x); lo.y = f2b(a.y); lo.z = f2b(a.z); lo.w = f2b(a.w);
        hi.x = f2b(bb.x); hi.y = f2b(bb.y); hi.z = f2b(bb.z); hi.w = f2b(bb.w);
        u16* dst = (tile == 0 ? &sUq[rr][c8] : &sUk[rr][c8]);
        *(ushort4*)dst = lo;
        *(ushort4*)(dst + 4) = hi;
      } else {
        // FIX: copy the full 8 u16 per slot (was ushort4 -> half-garbage tile)
        const u16* src = (tile == 2 ? Wq : Wk) + (size_t)rr * 384 + k0 + c8;
        u16* dst = (tile == 2 ? &sWq[rr][c8] : &sWk[rr][c8]);
        *(int4*)dst = *(const int4*)src;
      }
    }
    __syncthreads();
    if (wid < 3) {
      bf16x8 uq = *(const bf16x8*)(&sUq[wid * 16 + r][q8]);
#pragma unroll
      for (int j = 0; j < 3; j++) {
        bf16x8 wk = *(const bf16x8*)(&sWk[j * 16 + r][q8]);
        accS[j] = __builtin_amdgcn_mfma_f32_16x16x32_bf16(uq, wk, accS[j], 0, 0, 0);
      }
    } else {
#pragma unroll
      for (int i = 0; i < 3; i++) {
        bf16x8 uq = *(const bf16x8*)(&sUq[i * 16 + r][q8]);
        bf16x8 wq = *(const bf16x8*)(&sWq[i * 16 + r][q8]);
        bf16x8 uk = *(const bf16x8*)(&sUk[i * 16 + r][q8]);
        bf16x8 wk = *(const bf16x8*)(&sWk[i * 16 + r][q8]);
        accD[i]     = __builtin_amdgcn_mfma_f32_16x16x32_bf16(uq, wq, accD[i], 0, 0, 0);
        accD[3 + i] = __builtin_amdgcn_mfma_f32_16x16x32_bf16(uk, wk, accD[3 + i], 0, 0, 0);
      }
    }
    __syncthreads();
  }
  if (wid == 3) {
#pragma unroll
    for (int i = 0; i < 3; i++)
#pragma unroll
      for (int v = 0; v < 4; v++)
        if (r == quad * 4 + v) {
          sSsq[i * 16 + r] = accD[i][v];
          sSsq[48 + i * 16 + r] = accD[3 + i][v];
        }
  }
  __syncthreads();
  if (t < 96) sInv[t] = 1.f / fmaxf(sqrtf(sSsq[t]), 1e-12f);
  __syncthreads();
  // zero-pad sA cols 48..63
  for (int idx = t; idx < 48 * 16; idx += 256) sA[idx >> 4][48 + (idx & 15)] = 0;
  float T = temp[h];
  if (wid < 3) {
    float L[3][4];
    int c_base = wid * 16 + quad * 4;
#pragma unroll
    for (int j = 0; j < 3; j++)
#pragma unroll
      for (int v = 0; v < 4; v++)
        L[j][v] = accS[j][v] * sInv[c_base + v] * sInv[48 + j * 16 + r] * T;
    float mx[4], sum[4];
#pragma unroll
    for (int v = 0; v < 4; v++) mx[v] = fmaxf(fmaxf(L[0][v], L[1][v]), L[2][v]);
#pragma unroll
    for (int m = 1; m <= 8; m <<= 1)
#pragma unroll
      for (int v = 0; v < 4; v++) mx[v] = fmaxf(mx[v], __shfl_xor(mx[v], m));
#pragma unroll
    for (int v = 0; v < 4; v++) sum[v] = 0.f;
#pragma unroll
    for (int j = 0; j < 3; j++)
#pragma unroll
      for (int v = 0; v < 4; v++) { L[j][v] = __expf(L[j][v] - mx[v]); sum[v] += L[j][v]; }
#pragma unroll
    for (int m = 1; m <= 8; m <<= 1)
#pragma unroll
      for (int v = 0; v < 4; v++) sum[v] += __shfl_xor(sum[v], m);
#pragma unroll
    for (int j = 0; j < 3; j++)
#pragma unroll
      for (int v = 0; v < 4; v++)
        sA[c_base + v][j * 16 + r] = f2b(L[j][v] / sum[v]);
  }
  __syncthreads();
  // M[c][j] = sum_d A[c][d] WvT[j][d], K=64 (d padded). Output MT[j][e].
  const u16* WvTh = wvT + (size_t)h * 24576;
  floatx4 accM[3][6] = {};
#pragma unroll
  for (int ks = 0; ks < 2; ks++) {
    bf16x8 af[3];
#pragma unroll
    for (int i = 0; i < 3; i++) af[i] = *(const bf16x8*)(&sA[i * 16 + r][ks * 32 + q8]);
#pragma unroll
    for (int jj = 0; jj < 6; jj++) {
      int j = wid * 96 + jj * 16 + r;
      bf16x8 bb = *(const bf16x8*)(WvTh + (size_t)j * 64 + ks * 32 + q8);
#pragma unroll
      for (int i = 0; i < 3; i++)
        accM[i][jj] = __builtin_amdgcn_mfma_f32_16x16x32_bf16(af[i], bb, accM[i][jj], 0, 0, 0);
    }
  }
  u16* MTb = MT + (size_t)b * 147456;
#pragma unroll
  for (int i = 0; i < 3; i++)
#pragma unroll
    for (int jj = 0; jj < 6; jj++)
#pragma unroll
      for (int v = 0; v < 4; v++) {
        int c = i * 16 + quad * 4 + v;
        int j = wid * 96 + jj * 16 + r;
        MTb[(size_t)j * 384 + h * C_ + c] = f2b(accM[i][jj][v]);
      }
}

// ---------------- mid3: R[b][f][j] = sum_e P[f][e] MT[b][j][e], bf16 out ----
// grid (9 tile-combos, 32 b).
__global__ __launch_bounds__(256) void k_mid3(const u16* __restrict__ pwbf,
                                              const u16* __restrict__ MT,
                                              u16* __restrict__ R) {
  int m0 = (blockIdx.x % 3) * 128, n0 = (blockIdx.x / 3) * 128, b = blockIdx.y;
  __shared__ u16 As[2][128][32];
  __shared__ u16 Bs[2][128][32];
  int t = threadIdx.x, wid = t >> 6, lane = t & 63;
  int srow = wid * 32 + (lane >> 2), scol = (lane & 3) * 8;
  int wm = (wid & 1) * 64, wn = (wid >> 1) * 64;
  int r = lane & 15, quad = lane >> 4, q8 = quad * 8;
  const u16* gA = pwbf + (size_t)(m0 + srow) * 384 + scol;
  const u16* gB = MT + (size_t)b * 147456 + (size_t)(n0 + srow) * 384 + scol;

  floatx4 acc[4][4] = {};
  for (int k0 = 0; k0 < 384; k0 += 64) {
#pragma unroll
    for (int ks = 0; ks < 2; ks++) {
      gload16(gA + k0 + ks * 32,            &As[ks][wid * 32][0]);
      gload16(gA + k0 + ks * 32 + 16 * 384, &As[ks][wid * 32 + 16][0]);
      gload16(gB + k0 + ks * 32,            &Bs[ks][wid * 32][0]);
      gload16(gB + k0 + ks * 32 + 16 * 384, &Bs[ks][wid * 32 + 16][0]);
    }
    __syncthreads();
#pragma unroll
    for (int ks = 0; ks < 2; ks++) {
      bf16x8 af[4], bf[4];
#pragma unroll
      for (int i = 0; i < 4; i++) af[i] = *(const bf16x8*)(&As[ks][wm + i * 16 + r][q8]);
#pragma unroll
      for (int j = 0; j < 4; j++) bf[j] = *(const bf16x8*)(&Bs[ks][wn + j * 16 + r][q8]);
#pragma unroll
      for (int i = 0; i < 4; i++)
#pragma unroll
        for (int j = 0; j < 4; j++)
          acc[i][j] = __builtin_amdgcn_mfma_f32_16x16x32_bf16(af[i], bf[j], acc[i][j], 0, 0, 0);
    }
    __syncthreads();
  }
  u16* Rb = R + (size_t)b * 147456;
#pragma unroll
  for (int i = 0; i < 4; i++)
#pragma unroll
    for (int j = 0; j < 4; j++)
#pragma unroll
      for (int v = 0; v < 4; v++) {
        int rr = m0 + wm + i * 16 + quad * 4 + v;
        int cc = n0 + wn + j * 16 + r;
        Rb[(size_t)rr * 384 + cc] = f2b(acc[i][j][v]);
      }
}

// ---------------- final: Y[g][f] = sum_j xbf[g][j] R_b[f][j] + bias[f] ------
// 64x128 tile, grid (3 f-tiles, 1568 g-tiles), XCD-chunked swizzle (4704=8x588)
__global__ __launch_bounds__(256) void k_final(const u16* __restrict__ xbf,
                                               const u16* __restrict__ R,
                                               const float* __restrict__ bias,
                                               float* __restrict__ Y) {
  int lin = blockIdx.y * 3 + blockIdx.x;
  int w = (lin & 7) * 588 + (lin >> 3);
  int ft = w % 3, gt = w / 3;
  int b = gt / 49, n0 = (gt % 49) * 64;
  size_t g0 = (size_t)b * N_ + n0;
  int f0 = ft * 128;
  __shared__ u16 As[2][64][32];
  __shared__ u16 Bs[2][128][32];
  int t = threadIdx.x, wid = t >> 6, lane = t & 63;
  int srow = t >> 2, scol = (t & 3) * 8;
  int wm = (wid & 1) * 32, wn = (wid >> 1) * 64;
  int r = lane & 15, quad = lane >> 4, q8 = quad * 8;
  const u16* gA = xbf + (g0 + srow) * 384 + scol;
  const u16* gB1 = R + (size_t)b * 147456 + (size_t)(f0 + srow) * 384 + scol;
  const u16* gB2 = gB1 + (size_t)64 * 384;

  floatx4 acc[2][4] = {};
  for (int k0 = 0; k0 < 384; k0 += 64) {
#pragma unroll
    for (int ks = 0; ks < 2; ks++) {
      gload16(gA + k0 + ks * 32,  &As[ks][wid * 16][0]);
      gload16(gB1 + k0 + ks * 32, &Bs[ks][wid * 16][0]);
      gload16(gB2 + k0 + ks * 32, &Bs[ks][64 + wid * 16][0]);
    }
    __syncthreads();
#pragma unroll
    for (int ks = 0; ks < 2; ks++) {
      bf16x8 af[2], bf[4];
#pragma unroll
      for (int i = 0; i < 2; i++) af[i] = *(const bf16x8*)(&As[ks][wm + i * 16 + r][q8]);
#pragma unroll
      for (int j = 0; j < 4; j++) bf[j] = *(const bf16x8*)(&Bs[ks][wn + j * 16 + r][q8]);
#pragma unroll
      for (int i = 0; i < 2; i++)
#pragma unroll
        for (int j = 0; j < 4; j++)
          acc[i][j] = __builtin_amdgcn_mfma_f32_16x16x32_bf16(af[i], bf[j], acc[i][j], 0, 0, 0);
    }
    __syncthreads();
  }
#pragma unroll
  for (int i = 0; i < 2; i++)
#pragma unroll
    for (int j = 0; j < 4; j++) {
      int cc = wn + j * 16 + r;
      float bv = bias[f0 + cc];
#pragma unroll
      for (int v = 0; v < 4; v++) {
        int rr = wm + i * 16 + quad * 4 + v;
        Y[(g0 + rr) * 384 + f0 + cc] = acc[i][j][v] + bv;
      }
    }
}

extern "C" void kernel_launch(void* const* d_in, const int* in_sizes, int n_in,
                              void* d_out, int out_size, void* d_ws, size_t ws_size,
                              hipStream_t stream) {
  const float* x      = (const float*)d_in[0];   // 32*3136*384
  const float* qkv_w  = (const float*)d_in[1];   // 1152*384
  const float* temp   = (const float*)d_in[2];   // 8
  const float* proj_w = (const float*)d_in[3];   // 384*384
  const float* proj_b = (const float*)d_in[4];   // 384
  float* out = (float*)d_out;

  // workspace layout (bytes)
  char* ws = (char*)d_ws;
  u16*   xbf  = (u16*)(ws);                     //  77,070,336  [g][d]
  u16*   xT   = (u16*)(ws + 77070336);          //  77,070,336  [d][g]
  u16*   wbf  = (u16*)(ws + 154140672);         //     884,736  [e][d]
  u16*   pwbf = (u16*)(ws + 155025408);         //     294,912  [f][e]
  u16*   wvT  = (u16*)(ws + 155320320);         //     393,216  [h][384][64]
  float* G    = (float*)(ws + 155713536);       //  18,874,368  [b][384][384]
  u16*   Gbf  = (u16*)(ws + 174587904);         //   9,437,184
  float* U    = (float*)(ws + 184025088);       //  37,748,736  [b][768][384]
  u16*   MT   = (u16*)(ws + 221773824);         //   9,437,184  [b][j][e]
  u16*   R    = (u16*)(ws + 231211008);         //   9,437,184  [b][f][j]

  hipMemsetAsync(G, 0, 18874368, stream);

  k_cvt_t<<<dim3(6, 49, 32), 256, 0, stream>>>(x, xbf, xT);
  k_cvt<<<432, 256, 0, stream>>>(qkv_w, wbf, 110592);
  k_cvt<<<144, 256, 0, stream>>>(proj_w, pwbf, 36864);
  k_wvt<<<8, 256, 0, stream>>>(qkv_w, wvT);

  k_gram<<<dim3(9, 32, 7), 256, 0, stream>>>(xT, G);
  k_cvt<<<4608, 256, 0, stream>>>(G, Gbf, 1179648);
  k_mid1<<<dim3(6, 3, 32), 256, 0, stream>>>(wbf, Gbf, U);
  k_mid2<<<256, 256, 0, stream>>>(U, wbf, wvT, temp, MT);
  k_mid3<<<dim3(9, 32), 256, 0, stream>>>(pwbf, MT, R);
  k_final<<<dim3(3, 1568), 256, 0, stream>>>(xbf, R, proj_b, out);
}

// Round 5
// 494.512 us; speedup vs baseline: 1.1999x; 1.1276x over previous
//
#include <hip/hip_runtime.h>

// XCA: cross-covariance attention, B=32 N=3136 D=384 H=8 C=48.
// Round 6 (resubmit): Gram-factored pipeline, atomic-free gram.
//   G_b = X_b^T X_b (split-2, two f32 partial buffers, plain stores)
//   Gbf = cvt(G0+G1) ; U = W_qk G ; S/ssq/softmax/M in k_mid2
//   R_b = P M_b ; Y_b = X_b R_b^T + bias
// XCD-chunked swizzles on gram/mid1/final; prep kernels merged.

typedef __bf16 bf16x8 __attribute__((ext_vector_type(8)));
typedef float floatx4 __attribute__((ext_vector_type(4)));
typedef unsigned short u16;

#define B_ 32
#define N_ 3136
#define D_ 384
#define H_ 8
#define C_ 48
#define BN_ 100352   // B_*N_

__device__ __forceinline__ u16 f2b(float f) {
  unsigned u = __builtin_bit_cast(unsigned, f);
  u += 0x7FFFu + ((u >> 16) & 1u);   // RNE
  return (u16)(u >> 16);
}
__device__ __forceinline__ void gload16(const u16* g, u16* l) {
  __builtin_amdgcn_global_load_lds(
      (const __attribute__((address_space(1))) void*)g,
      (__attribute__((address_space(3))) void*)l, 16, 0, 0);
}

// ---------------- cvt + transpose: x -> xbf [g][d] and xT [d][g] ------------
// grid (6 d-tiles, 49 n-tiles, 32 b), 64x64 tiles.
__global__ __launch_bounds__(256) void k_cvt_t(const float* __restrict__ x,
                                               u16* __restrict__ xbf,
                                               u16* __restrict__ xT) {
  int d0 = blockIdx.x * 64, n0 = blockIdx.y * 64, b = blockIdx.z;
  const float* xp = x + ((size_t)b * N_ + n0) * D_ + d0;
  __shared__ u16 L[64][68];
  int t = threadIdx.x;
  int nl = t >> 4, dl = (t & 15) * 4;
#pragma unroll
  for (int p = 0; p < 4; p++) {
    int n = nl + p * 16;
    float4 v = *(const float4*)(xp + (size_t)n * D_ + dl);
    ushort4 o;
    o.x = f2b(v.x); o.y = f2b(v.y); o.z = f2b(v.z); o.w = f2b(v.w);
    *(ushort4*)(xbf + ((size_t)(b * N_ + n0 + n)) * D_ + d0 + dl) = o;
    *(ushort4*)(&L[n][dl]) = o;
  }
  __syncthreads();
  int dl2 = t >> 4, nl2 = (t & 15) * 4;
#pragma unroll
  for (int p = 0; p < 4; p++) {
    int d = dl2 + p * 16;
    ushort4 o;
    o.x = L[nl2 + 0][d]; o.y = L[nl2 + 1][d];
    o.z = L[nl2 + 2][d]; o.w = L[nl2 + 3][d];
    *(ushort4*)(xT + (size_t)(d0 + d) * BN_ + b * N_ + n0 + nl2) = o;
  }
}

// ---------------- merged prep: wbf, pwbf, wvT -------------------------------
// blocks 0..431: qkv_w cvt; 432..575: proj_w cvt; 576..583: wvT build.
__global__ __launch_bounds__(256) void k_prep(const float* __restrict__ qkv_w,
                                              const float* __restrict__ proj_w,
                                              u16* __restrict__ wbf,
                                              u16* __restrict__ pwbf,
                                              u16* __restrict__ wvT) {
  int blk = blockIdx.x, t = threadIdx.x;
  if (blk < 432) {
    int i = blk * 256 + t;
    float4 v = ((const float4*)qkv_w)[i];
    ushort4 o;
    o.x = f2b(v.x); o.y = f2b(v.y); o.z = f2b(v.z); o.w = f2b(v.w);
    ((ushort4*)wbf)[i] = o;
  } else if (blk < 576) {
    int i = (blk - 432) * 256 + t;
    float4 v = ((const float4*)proj_w)[i];
    ushort4 o;
    o.x = f2b(v.x); o.y = f2b(v.y); o.z = f2b(v.z); o.w = f2b(v.w);
    ((ushort4*)pwbf)[i] = o;
  } else {
    int h = blk - 576;
    for (int idx = t; idx < 384 * 64; idx += 256) {
      int j = idx >> 6, d = idx & 63;
      float v = (d < 48) ? qkv_w[(size_t)(2 * D_ + h * C_ + d) * D_ + j] : 0.f;
      wvT[(size_t)h * 24576 + idx] = f2b(v);
    }
  }
}

// ---------------- gram: G_part[split][b] = xT[m] . xT[n]^T over its n-range -
// grid 576 1D; XCD-chunk swizzle (8 x 72, b-major). Splits 1600/1536 tokens.
// Plain f32 stores (no atomics).
__global__ __launch_bounds__(256) void k_gram(const u16* __restrict__ xT,
                                              float* __restrict__ G) {
  int lin = blockIdx.x;
  int w = (lin & 7) * 72 + (lin >> 3);
  int b = w / 18, rem = w % 18;
  int split = rem / 9, tile = rem % 9;
  int m0 = (tile % 3) * 128, n0 = (tile / 3) * 128;
  int kbeg = split * 1600, klen = split ? 1536 : 1600;
  __shared__ u16 As[2][128][32];
  __shared__ u16 Bs[2][128][32];
  int t = threadIdx.x, wid = t >> 6, lane = t & 63;
  int srow = wid * 32 + (lane >> 2), scol = (lane & 3) * 8;
  int wm = (wid & 1) * 64, wn = (wid >> 1) * 64;
  int r = lane & 15, quad = lane >> 4, q8 = quad * 8;
  const u16* base = xT + (size_t)b * N_ + kbeg + scol;
  const u16* gA = base + (size_t)(m0 + srow) * BN_;
  const u16* gB = base + (size_t)(n0 + srow) * BN_;

  floatx4 acc[4][4] = {};
  for (int k0 = 0; k0 < klen; k0 += 64) {
#pragma unroll
    for (int ks = 0; ks < 2; ks++) {
      gload16(gA + k0 + ks * 32,                     &As[ks][wid * 32][0]);
      gload16(gA + k0 + ks * 32 + (size_t)16 * BN_,  &As[ks][wid * 32 + 16][0]);
      gload16(gB + k0 + ks * 32,                     &Bs[ks][wid * 32][0]);
      gload16(gB + k0 + ks * 32 + (size_t)16 * BN_,  &Bs[ks][wid * 32 + 16][0]);
    }
    __syncthreads();
#pragma unroll
    for (int ks = 0; ks < 2; ks++) {
      bf16x8 af[4], bf[4];
#pragma unroll
      for (int i = 0; i < 4; i++) af[i] = *(const bf16x8*)(&As[ks][wm + i * 16 + r][q8]);
#pragma unroll
      for (int j = 0; j < 4; j++) bf[j] = *(const bf16x8*)(&Bs[ks][wn + j * 16 + r][q8]);
#pragma unroll
      for (int i = 0; i < 4; i++)
#pragma unroll
        for (int j = 0; j < 4; j++)
          acc[i][j] = __builtin_amdgcn_mfma_f32_16x16x32_bf16(af[i], bf[j], acc[i][j], 0, 0, 0);
    }
    __syncthreads();
  }
  float* Gp = G + (size_t)split * 4718592 + (size_t)b * 147456;
#pragma unroll
  for (int i = 0; i < 4; i++)
#pragma unroll
    for (int j = 0; j < 4; j++)
#pragma unroll
      for (int v = 0; v < 4; v++) {
        int rr = m0 + wm + i * 16 + quad * 4 + v;
        int cc = n0 + wn + j * 16 + r;
        Gp[(size_t)rr * 384 + cc] = acc[i][j][v];
      }
}

// ---------------- gsum: Gbf = cvt(G0 + G1) ----------------------------------
__global__ __launch_bounds__(256) void k_gsum(const float* __restrict__ G,
                                              u16* __restrict__ Gbf) {
  int i = blockIdx.x * 256 + threadIdx.x;   // 4608*256 = 1,179,648 float4s
  float4 a = ((const float4*)G)[i];
  float4 b = ((const float4*)(G + 4718592))[i];
  ushort4 o;
  o.x = f2b(a.x + b.x); o.y = f2b(a.y + b.y);
  o.z = f2b(a.z + b.z); o.w = f2b(a.w + b.w);
  ((ushort4*)Gbf)[i] = o;
}

// ---------------- mid1: U[b][e][j] = sum_i Wqk[e][i] G[b][j][i] (G sym) -----
// grid 576 1D, XCD-chunk swizzle (8 x 72, b-major). Output f32.
__global__ __launch_bounds__(256) void k_mid1(const u16* __restrict__ wbf,
                                              const u16* __restrict__ Gb,
                                              float* __restrict__ U) {
  int lin = blockIdx.x;
  int w = (lin & 7) * 72 + (lin >> 3);
  int b = w / 18, rem = w % 18;
  int m0 = (rem / 3) * 128, n0 = (rem % 3) * 128;
  __shared__ u16 As[2][128][32];
  __shared__ u16 Bs[2][128][32];
  int t = threadIdx.x, wid = t >> 6, lane = t & 63;
  int srow = wid * 32 + (lane >> 2), scol = (lane & 3) * 8;
  int wm = (wid & 1) * 64, wn = (wid >> 1) * 64;
  int r = lane & 15, quad = lane >> 4, q8 = quad * 8;
  const u16* gA = wbf + (size_t)(m0 + srow) * 384 + scol;
  const u16* gB = Gb + (size_t)b * 147456 + (size_t)(n0 + srow) * 384 + scol;

  floatx4 acc[4][4] = {};
  for (int k0 = 0; k0 < 384; k0 += 64) {
#pragma unroll
    for (int ks = 0; ks < 2; ks++) {
      gload16(gA + k0 + ks * 32,            &As[ks][wid * 32][0]);
      gload16(gA + k0 + ks * 32 + 16 * 384, &As[ks][wid * 32 + 16][0]);
      gload16(gB + k0 + ks * 32,            &Bs[ks][wid * 32][0]);
      gload16(gB + k0 + ks * 32 + 16 * 384, &Bs[ks][wid * 32 + 16][0]);
    }
    __syncthreads();
#pragma unroll
    for (int ks = 0; ks < 2; ks++) {
      bf16x8 af[4], bf[4];
#pragma unroll
      for (int i = 0; i < 4; i++) af[i] = *(const bf16x8*)(&As[ks][wm + i * 16 + r][q8]);
#pragma unroll
      for (int j = 0; j < 4; j++) bf[j] = *(const bf16x8*)(&Bs[ks][wn + j * 16 + r][q8]);
#pragma unroll
      for (int i = 0; i < 4; i++)
#pragma unroll
        for (int j = 0; j < 4; j++)
          acc[i][j] = __builtin_amdgcn_mfma_f32_16x16x32_bf16(af[i], bf[j], acc[i][j], 0, 0, 0);
    }
    __syncthreads();
  }
  float* Ub = U + (size_t)b * 294912;
#pragma unroll
  for (int i = 0; i < 4; i++)
#pragma unroll
    for (int j = 0; j < 4; j++)
#pragma unroll
      for (int v = 0; v < 4; v++) {
        int rr = m0 + wm + i * 16 + quad * 4 + v;
        int cc = n0 + wn + j * 16 + r;
        Ub[(size_t)rr * 384 + cc] = acc[i][j][v];
      }
}

// ---------------- mid2: per bh: S, ssq (MFMA diag), softmax, M = A Wv -------
// Writes MT[b][j][e] bf16 (transposed M for mid3's B-operand).
__global__ __launch_bounds__(256) void k_mid2(const float* __restrict__ U,
                                              const u16* __restrict__ wbf,
                                              const u16* __restrict__ wvT,
                                              const float* __restrict__ temp,
                                              u16* __restrict__ MT) {
  int bh = blockIdx.x, b = bh >> 3, h = bh & 7;
  __shared__ __align__(16) u16 sUq[48][32], sUk[48][32], sWq[48][32], sWk[48][32];
  __shared__ __align__(16) u16 sA[48][72];
  __shared__ float sSsq[96];
  __shared__ float sInv[96];
  int t = threadIdx.x, wid = t >> 6, lane = t & 63;
  int r = lane & 15, quad = lane >> 4, q8 = quad * 8;
  const float* Uq = U + (size_t)b * 294912 + (size_t)(h * C_) * 384;
  const float* Uk = U + (size_t)b * 294912 + (size_t)(D_ + h * C_) * 384;
  const u16* Wq = wbf + (size_t)(h * C_) * 384;
  const u16* Wk = wbf + (size_t)(D_ + h * C_) * 384;

  floatx4 accS[3] = {};
  floatx4 accD[6] = {};
  for (int k0 = 0; k0 < 384; k0 += 32) {
    for (int idx = t; idx < 768; idx += 256) {
      int tile = idx / 192, rem = idx - tile * 192;
      int rr = rem >> 2, c8 = (rem & 3) * 8;
      if (tile < 2) {
        const float* src = (tile == 0 ? Uq : Uk) + (size_t)rr * 384 + k0 + c8;
        float4 a = *(const float4*)src;
        float4 bb = *(const float4*)(src + 4);
        ushort4 lo, hi;
        lo.x = f2b(a.x); lo.y = f2b(a.y); lo.z = f2b(a.z); lo.w = f2b(a.w);
        hi.x = f2b(bb.x); hi.y = f2b(bb.y); hi.z = f2b(bb.z); hi.w = f2b(bb.w);
        u16* dst = (tile == 0 ? &sUq[rr][c8] : &sUk[rr][c8]);
        *(ushort4*)dst = lo;
        *(ushort4*)(dst + 4) = hi;
      } else {
        const u16* src = (tile == 2 ? Wq : Wk) + (size_t)rr * 384 + k0 + c8;
        u16* dst = (tile == 2 ? &sWq[rr][c8] : &sWk[rr][c8]);
        *(int4*)dst = *(const int4*)src;
      }
    }
    __syncthreads();
    if (wid < 3) {
      bf16x8 uq = *(const bf16x8*)(&sUq[wid * 16 + r][q8]);
#pragma unroll
      for (int j = 0; j < 3; j++) {
        bf16x8 wk = *(const bf16x8*)(&sWk[j * 16 + r][q8]);
        accS[j] = __builtin_amdgcn_mfma_f32_16x16x32_bf16(uq, wk, accS[j], 0, 0, 0);
      }
    } else {
#pragma unroll
      for (int i = 0; i < 3; i++) {
        bf16x8 uq = *(const bf16x8*)(&sUq[i * 16 + r][q8]);
        bf16x8 wq = *(const bf16x8*)(&sWq[i * 16 + r][q8]);
        bf16x8 uk = *(const bf16x8*)(&sUk[i * 16 + r][q8]);
        bf16x8 wk = *(const bf16x8*)(&sWk[i * 16 + r][q8]);
        accD[i]     = __builtin_amdgcn_mfma_f32_16x16x32_bf16(uq, wq, accD[i], 0, 0, 0);
        accD[3 + i] = __builtin_amdgcn_mfma_f32_16x16x32_bf16(uk, wk, accD[3 + i], 0, 0, 0);
      }
    }
    __syncthreads();
  }
  if (wid == 3) {
#pragma unroll
    for (int i = 0; i < 3; i++)
#pragma unroll
      for (int v = 0; v < 4; v++)
        if (r == quad * 4 + v) {
          sSsq[i * 16 + r] = accD[i][v];
          sSsq[48 + i * 16 + r] = accD[3 + i][v];
        }
  }
  __syncthreads();
  if (t < 96) sInv[t] = 1.f / fmaxf(sqrtf(sSsq[t]), 1e-12f);
  __syncthreads();
  // zero-pad sA cols 48..63
  for (int idx = t; idx < 48 * 16; idx += 256) sA[idx >> 4][48 + (idx & 15)] = 0;
  float T = temp[h];
  if (wid < 3) {
    float L[3][4];
    int c_base = wid * 16 + quad * 4;
#pragma unroll
    for (int j = 0; j < 3; j++)
#pragma unroll
      for (int v = 0; v < 4; v++)
        L[j][v] = accS[j][v] * sInv[c_base + v] * sInv[48 + j * 16 + r] * T;
    float mx[4], sum[4];
#pragma unroll
    for (int v = 0; v < 4; v++) mx[v] = fmaxf(fmaxf(L[0][v], L[1][v]), L[2][v]);
#pragma unroll
    for (int m = 1; m <= 8; m <<= 1)
#pragma unroll
      for (int v = 0; v < 4; v++) mx[v] = fmaxf(mx[v], __shfl_xor(mx[v], m));
#pragma unroll
    for (int v = 0; v < 4; v++) sum[v] = 0.f;
#pragma unroll
    for (int j = 0; j < 3; j++)
#pragma unroll
      for (int v = 0; v < 4; v++) { L[j][v] = __expf(L[j][v] - mx[v]); sum[v] += L[j][v]; }
#pragma unroll
    for (int m = 1; m <= 8; m <<= 1)
#pragma unroll
      for (int v = 0; v < 4; v++) sum[v] += __shfl_xor(sum[v], m);
#pragma unroll
    for (int j = 0; j < 3; j++)
#pragma unroll
      for (int v = 0; v < 4; v++)
        sA[c_base + v][j * 16 + r] = f2b(L[j][v] / sum[v]);
  }
  __syncthreads();
  // M[c][j] = sum_d A[c][d] WvT[j][d], K=64 (d padded). Output MT[j][e].
  const u16* WvTh = wvT + (size_t)h * 24576;
  floatx4 accM[3][6] = {};
#pragma unroll
  for (int ks = 0; ks < 2; ks++) {
    bf16x8 af[3];
#pragma unroll
    for (int i = 0; i < 3; i++) af[i] = *(const bf16x8*)(&sA[i * 16 + r][ks * 32 + q8]);
#pragma unroll
    for (int jj = 0; jj < 6; jj++) {
      int j = wid * 96 + jj * 16 + r;
      bf16x8 bb = *(const bf16x8*)(WvTh + (size_t)j * 64 + ks * 32 + q8);
#pragma unroll
      for (int i = 0; i < 3; i++)
        accM[i][jj] = __builtin_amdgcn_mfma_f32_16x16x32_bf16(af[i], bb, accM[i][jj], 0, 0, 0);
    }
  }
  u16* MTb = MT + (size_t)b * 147456;
#pragma unroll
  for (int i = 0; i < 3; i++)
#pragma unroll
    for (int jj = 0; jj < 6; jj++)
#pragma unroll
      for (int v = 0; v < 4; v++) {
        int c = i * 16 + quad * 4 + v;
        int j = wid * 96 + jj * 16 + r;
        MTb[(size_t)j * 384 + h * C_ + c] = f2b(accM[i][jj][v]);
      }
}

// ---------------- mid3: R[b][f][j] = sum_e P[f][e] MT[b][j][e], bf16 out ----
// grid (9 tile-combos, 32 b).
__global__ __launch_bounds__(256) void k_mid3(const u16* __restrict__ pwbf,
                                              const u16* __restrict__ MT,
                                              u16* __restrict__ R) {
  int m0 = (blockIdx.x % 3) * 128, n0 = (blockIdx.x / 3) * 128, b = blockIdx.y;
  __shared__ u16 As[2][128][32];
  __shared__ u16 Bs[2][128][32];
  int t = threadIdx.x, wid = t >> 6, lane = t & 63;
  int srow = wid * 32 + (lane >> 2), scol = (lane & 3) * 8;
  int wm = (wid & 1) * 64, wn = (wid >> 1) * 64;
  int r = lane & 15, quad = lane >> 4, q8 = quad * 8;
  const u16* gA = pwbf + (size_t)(m0 + srow) * 384 + scol;
  const u16* gB = MT + (size_t)b * 147456 + (size_t)(n0 + srow) * 384 + scol;

  floatx4 acc[4][4] = {};
  for (int k0 = 0; k0 < 384; k0 += 64) {
#pragma unroll
    for (int ks = 0; ks < 2; ks++) {
      gload16(gA + k0 + ks * 32,            &As[ks][wid * 32][0]);
      gload16(gA + k0 + ks * 32 + 16 * 384, &As[ks][wid * 32 + 16][0]);
      gload16(gB + k0 + ks * 32,            &Bs[ks][wid * 32][0]);
      gload16(gB + k0 + ks * 32 + 16 * 384, &Bs[ks][wid * 32 + 16][0]);
    }
    __syncthreads();
#pragma unroll
    for (int ks = 0; ks < 2; ks++) {
      bf16x8 af[4], bf[4];
#pragma unroll
      for (int i = 0; i < 4; i++) af[i] = *(const bf16x8*)(&As[ks][wm + i * 16 + r][q8]);
#pragma unroll
      for (int j = 0; j < 4; j++) bf[j] = *(const bf16x8*)(&Bs[ks][wn + j * 16 + r][q8]);
#pragma unroll
      for (int i = 0; i < 4; i++)
#pragma unroll
        for (int j = 0; j < 4; j++)
          acc[i][j] = __builtin_amdgcn_mfma_f32_16x16x32_bf16(af[i], bf[j], acc[i][j], 0, 0, 0);
    }
    __syncthreads();
  }
  u16* Rb = R + (size_t)b * 147456;
#pragma unroll
  for (int i = 0; i < 4; i++)
#pragma unroll
    for (int j = 0; j < 4; j++)
#pragma unroll
      for (int v = 0; v < 4; v++) {
        int rr = m0 + wm + i * 16 + quad * 4 + v;
        int cc = n0 + wn + j * 16 + r;
        Rb[(size_t)rr * 384 + cc] = f2b(acc[i][j][v]);
      }
}

// ---------------- final: Y[g][f] = sum_j xbf[g][j] R_b[f][j] + bias[f] ------
// 64x128 tile, grid (3 f-tiles, 1568 g-tiles), XCD-chunked swizzle (4704=8x588)
__global__ __launch_bounds__(256) void k_final(const u16* __restrict__ xbf,
                                               const u16* __restrict__ R,
                                               const float* __restrict__ bias,
                                               float* __restrict__ Y) {
  int lin = blockIdx.y * 3 + blockIdx.x;
  int w = (lin & 7) * 588 + (lin >> 3);
  int ft = w % 3, gt = w / 3;
  int b = gt / 49, n0 = (gt % 49) * 64;
  size_t g0 = (size_t)b * N_ + n0;
  int f0 = ft * 128;
  __shared__ u16 As[2][64][32];
  __shared__ u16 Bs[2][128][32];
  int t = threadIdx.x, wid = t >> 6, lane = t & 63;
  int srow = t >> 2, scol = (t & 3) * 8;
  int wm = (wid & 1) * 32, wn = (wid >> 1) * 64;
  int r = lane & 15, quad = lane >> 4, q8 = quad * 8;
  const u16* gA = xbf + (g0 + srow) * 384 + scol;
  const u16* gB1 = R + (size_t)b * 147456 + (size_t)(f0 + srow) * 384 + scol;
  const u16* gB2 = gB1 + (size_t)64 * 384;

  floatx4 acc[2][4] = {};
  for (int k0 = 0; k0 < 384; k0 += 64) {
#pragma unroll
    for (int ks = 0; ks < 2; ks++) {
      gload16(gA + k0 + ks * 32,  &As[ks][wid * 16][0]);
      gload16(gB1 + k0 + ks * 32, &Bs[ks][wid * 16][0]);
      gload16(gB2 + k0 + ks * 32, &Bs[ks][64 + wid * 16][0]);
    }
    __syncthreads();
#pragma unroll
    for (int ks = 0; ks < 2; ks++) {
      bf16x8 af[2], bf[4];
#pragma unroll
      for (int i = 0; i < 2; i++) af[i] = *(const bf16x8*)(&As[ks][wm + i * 16 + r][q8]);
#pragma unroll
      for (int j = 0; j < 4; j++) bf[j] = *(const bf16x8*)(&Bs[ks][wn + j * 16 + r][q8]);
#pragma unroll
      for (int i = 0; i < 2; i++)
#pragma unroll
        for (int j = 0; j < 4; j++)
          acc[i][j] = __builtin_amdgcn_mfma_f32_16x16x32_bf16(af[i], bf[j], acc[i][j], 0, 0, 0);
    }
    __syncthreads();
  }
#pragma unroll
  for (int i = 0; i < 2; i++)
#pragma unroll
    for (int j = 0; j < 4; j++) {
      int cc = wn + j * 16 + r;
      float bv = bias[f0 + cc];
#pragma unroll
      for (int v = 0; v < 4; v++) {
        int rr = wm + i * 16 + quad * 4 + v;
        Y[(g0 + rr) * 384 + f0 + cc] = acc[i][j][v] + bv;
      }
    }
}

extern "C" void kernel_launch(void* const* d_in, const int* in_sizes, int n_in,
                              void* d_out, int out_size, void* d_ws, size_t ws_size,
                              hipStream_t stream) {
  const float* x      = (const float*)d_in[0];   // 32*3136*384
  const float* qkv_w  = (const float*)d_in[1];   // 1152*384
  const float* temp   = (const float*)d_in[2];   // 8
  const float* proj_w = (const float*)d_in[3];   // 384*384
  const float* proj_b = (const float*)d_in[4];   // 384
  float* out = (float*)d_out;

  // workspace layout (bytes)
  char* ws = (char*)d_ws;
  u16*   xbf  = (u16*)(ws);                     //  77,070,336  [g][d]
  u16*   xT   = (u16*)(ws + 77070336);          //  77,070,336  [d][g]
  u16*   wbf  = (u16*)(ws + 154140672);         //     884,736  [e][d]
  u16*   pwbf = (u16*)(ws + 155025408);         //     294,912  [f][e]
  u16*   wvT  = (u16*)(ws + 155320320);         //     393,216  [h][384][64]
  float* G    = (float*)(ws + 155713536);       //  37,748,736  [2][b][384][384]
  u16*   Gbf  = (u16*)(ws + 193462272);         //   9,437,184
  float* U    = (float*)(ws + 202899456);       //  37,748,736  [b][768][384]
  u16*   MT   = (u16*)(ws + 240648192);         //   9,437,184  [b][j][e]
  u16*   R    = (u16*)(ws + 250085376);         //   9,437,184  [b][f][j]

  k_cvt_t<<<dim3(6, 49, 32), 256, 0, stream>>>(x, xbf, xT);
  k_prep<<<584, 256, 0, stream>>>(qkv_w, proj_w, wbf, pwbf, wvT);

  k_gram<<<576, 256, 0, stream>>>(xT, G);
  k_gsum<<<4608, 256, 0, stream>>>(G, Gbf);
  k_mid1<<<576, 256, 0, stream>>>(wbf, Gbf, U);
  k_mid2<<<256, 256, 0, stream>>>(U, wbf, wvT, temp, MT);
  k_mid3<<<dim3(9, 32), 256, 0, stream>>>(pwbf, MT, R);
  k_final<<<dim3(3, 1568), 256, 0, stream>>>(xbf, R, proj_b, out);
}

// Round 6
// 486.905 us; speedup vs baseline: 1.2187x; 1.0156x over previous
//
#include <hip/hip_runtime.h>

// XCA: cross-covariance attention, B=32 N=3136 D=384 H=8 C=48.
// Round 7: Gram-factored pipeline.
//   - gram exploits symmetry: 6 upper-triangle 128^2 tiles (not 9); gsum
//     sums the 2 split partials, converts to bf16, and mirrors off-diag.
//   - mid1 emits U as bf16 (same rounding point; halves U traffic).
//   - final is the 128x128 m97 BK=64 structure with XCD swizzle (2400=8x300),
//     tail g-tile handled by C-write guard.
//   - cvt_t + weight prep fused into one kernel (k_entry).

typedef __bf16 bf16x8 __attribute__((ext_vector_type(8)));
typedef float floatx4 __attribute__((ext_vector_type(4)));
typedef unsigned short u16;

#define B_ 32
#define N_ 3136
#define D_ 384
#define H_ 8
#define C_ 48
#define BN_ 100352   // B_*N_

__device__ __forceinline__ u16 f2b(float f) {
  unsigned u = __builtin_bit_cast(unsigned, f);
  u += 0x7FFFu + ((u >> 16) & 1u);   // RNE
  return (u16)(u >> 16);
}
__device__ __forceinline__ void gload16(const u16* g, u16* l) {
  __builtin_amdgcn_global_load_lds(
      (const __attribute__((address_space(1))) void*)g,
      (__attribute__((address_space(3))) void*)l, 16, 0, 0);
}

// ---------------- entry: cvt+transpose (blocks 0..9407) + weight prep -------
// cvt_t: x -> xbf [g][d], xT [d][g]; prep: wbf, pwbf, wvT.
__global__ __launch_bounds__(256) void k_entry(const float* __restrict__ x,
                                               const float* __restrict__ qkv_w,
                                               const float* __restrict__ proj_w,
                                               u16* __restrict__ xbf,
                                               u16* __restrict__ xT,
                                               u16* __restrict__ wbf,
                                               u16* __restrict__ pwbf,
                                               u16* __restrict__ wvT) {
  int lin = blockIdx.x, t = threadIdx.x;
  if (lin < 9408) {
    int b = lin / 294, rem = lin % 294;
    int n0 = (rem / 6) * 64, d0 = (rem % 6) * 64;
    const float* xp = x + ((size_t)b * N_ + n0) * D_ + d0;
    __shared__ u16 L[64][68];
    int nl = t >> 4, dl = (t & 15) * 4;
#pragma unroll
    for (int p = 0; p < 4; p++) {
      int n = nl + p * 16;
      float4 v = *(const float4*)(xp + (size_t)n * D_ + dl);
      ushort4 o;
      o.x = f2b(v.x); o.y = f2b(v.y); o.z = f2b(v.z); o.w = f2b(v.w);
      *(ushort4*)(xbf + ((size_t)(b * N_ + n0 + n)) * D_ + d0 + dl) = o;
      *(ushort4*)(&L[n][dl]) = o;
    }
    __syncthreads();
    int dl2 = t >> 4, nl2 = (t & 15) * 4;
#pragma unroll
    for (int p = 0; p < 4; p++) {
      int d = dl2 + p * 16;
      ushort4 o;
      o.x = L[nl2 + 0][d]; o.y = L[nl2 + 1][d];
      o.z = L[nl2 + 2][d]; o.w = L[nl2 + 3][d];
      *(ushort4*)(xT + (size_t)(d0 + d) * BN_ + b * N_ + n0 + nl2) = o;
    }
  } else {
    int blk = lin - 9408;
    if (blk < 432) {
      int i = blk * 256 + t;
      float4 v = ((const float4*)qkv_w)[i];
      ushort4 o;
      o.x = f2b(v.x); o.y = f2b(v.y); o.z = f2b(v.z); o.w = f2b(v.w);
      ((ushort4*)wbf)[i] = o;
    } else if (blk < 576) {
      int i = (blk - 432) * 256 + t;
      float4 v = ((const float4*)proj_w)[i];
      ushort4 o;
      o.x = f2b(v.x); o.y = f2b(v.y); o.z = f2b(v.z); o.w = f2b(v.w);
      ((ushort4*)pwbf)[i] = o;
    } else {
      int h = blk - 576;
      for (int idx = t; idx < 384 * 64; idx += 256) {
        int j = idx >> 6, d = idx & 63;
        float v = (d < 48) ? qkv_w[(size_t)(2 * D_ + h * C_ + d) * D_ + j] : 0.f;
        wvT[(size_t)h * 24576 + idx] = f2b(v);
      }
    }
  }
}

// ---------------- gram: 6 upper-tri tiles, split-2, plain f32 stores --------
// grid 384 1D; XCD swizzle 8x48. Partial layout [split][b][t6][128][128] f32.
__constant__ int c_ti[6] = {0, 0, 0, 1, 1, 2};
__constant__ int c_tj[6] = {0, 1, 2, 1, 2, 2};

__global__ __launch_bounds__(256) void k_gram(const u16* __restrict__ xT,
                                              float* __restrict__ G) {
  int lin = blockIdx.x;
  int w = (lin & 7) * 48 + (lin >> 3);
  int b = w / 12, rem = w % 12;
  int split = rem / 6, t6 = rem % 6;
  int m0 = c_ti[t6] * 128, n0 = c_tj[t6] * 128;
  int kbeg = split * 1600, klen = split ? 1536 : 1600;
  __shared__ u16 As[2][128][32];
  __shared__ u16 Bs[2][128][32];
  int t = threadIdx.x, wid = t >> 6, lane = t & 63;
  int srow = wid * 32 + (lane >> 2), scol = (lane & 3) * 8;
  int wm = (wid & 1) * 64, wn = (wid >> 1) * 64;
  int r = lane & 15, quad = lane >> 4, q8 = quad * 8;
  const u16* base = xT + (size_t)b * N_ + kbeg + scol;
  const u16* gA = base + (size_t)(m0 + srow) * BN_;
  const u16* gB = base + (size_t)(n0 + srow) * BN_;

  floatx4 acc[4][4] = {};
  for (int k0 = 0; k0 < klen; k0 += 64) {
#pragma unroll
    for (int ks = 0; ks < 2; ks++) {
      gload16(gA + k0 + ks * 32,                     &As[ks][wid * 32][0]);
      gload16(gA + k0 + ks * 32 + (size_t)16 * BN_,  &As[ks][wid * 32 + 16][0]);
      gload16(gB + k0 + ks * 32,                     &Bs[ks][wid * 32][0]);
      gload16(gB + k0 + ks * 32 + (size_t)16 * BN_,  &Bs[ks][wid * 32 + 16][0]);
    }
    __syncthreads();
#pragma unroll
    for (int ks = 0; ks < 2; ks++) {
      bf16x8 af[4], bf[4];
#pragma unroll
      for (int i = 0; i < 4; i++) af[i] = *(const bf16x8*)(&As[ks][wm + i * 16 + r][q8]);
#pragma unroll
      for (int j = 0; j < 4; j++) bf[j] = *(const bf16x8*)(&Bs[ks][wn + j * 16 + r][q8]);
#pragma unroll
      for (int i = 0; i < 4; i++)
#pragma unroll
        for (int j = 0; j < 4; j++)
          acc[i][j] = __builtin_amdgcn_mfma_f32_16x16x32_bf16(af[i], bf[j], acc[i][j], 0, 0, 0);
    }
    __syncthreads();
  }
  float* Gp = G + ((size_t)split * 192 + b * 6 + t6) * 16384;
#pragma unroll
  for (int i = 0; i < 4; i++)
#pragma unroll
    for (int j = 0; j < 4; j++)
#pragma unroll
      for (int v = 0; v < 4; v++) {
        int rr = wm + i * 16 + quad * 4 + v;
        int cc = wn + j * 16 + r;
        Gp[(size_t)rr * 128 + cc] = acc[i][j][v];
      }
}

// ---------------- gsum: Gbf = cvt(G0+G1), mirrored into full 384x384 --------
// grid 768: 4 parts per (b,t6). Off-diag tiles also scatter the transpose.
__global__ __launch_bounds__(256) void k_gsum(const float* __restrict__ G,
                                              u16* __restrict__ Gbf) {
  int gid = blockIdx.x, t = threadIdx.x;
  int tb = gid >> 2, part = gid & 3;
  int b = tb / 6, t6 = tb % 6;
  int ti = c_ti[t6], tj = c_tj[t6];
  const float* G0 = G + ((size_t)b * 6 + t6) * 16384;
  const float* G1 = G0 + (size_t)192 * 16384;
  u16* Gb = Gbf + (size_t)b * 147456;
#pragma unroll
  for (int it = 0; it < 4; it++) {
    int idx = part * 1024 + it * 256 + t;        // float4 index in tile
    int i = idx >> 5, j4 = (idx & 31) * 4;
    float4 a = ((const float4*)G0)[idx];
    float4 c = ((const float4*)G1)[idx];
    float s0 = a.x + c.x, s1 = a.y + c.y, s2 = a.z + c.z, s3 = a.w + c.w;
    ushort4 o;
    o.x = f2b(s0); o.y = f2b(s1); o.z = f2b(s2); o.w = f2b(s3);
    *(ushort4*)(Gb + (size_t)(ti * 128 + i) * 384 + tj * 128 + j4) = o;
    if (ti != tj) {
      int cbase = ti * 128 + i;
      Gb[(size_t)(tj * 128 + j4 + 0) * 384 + cbase] = o.x;
      Gb[(size_t)(tj * 128 + j4 + 1) * 384 + cbase] = o.y;
      Gb[(size_t)(tj * 128 + j4 + 2) * 384 + cbase] = o.z;
      Gb[(size_t)(tj * 128 + j4 + 3) * 384 + cbase] = o.w;
    }
  }
}

// ---------------- mid1: U[b][e][j] = sum_i Wqk[e][i] G[b][j][i], bf16 out ---
// grid 576 1D, XCD swizzle 8x72.
__global__ __launch_bounds__(256) void k_mid1(const u16* __restrict__ wbf,
                                              const u16* __restrict__ Gb,
                                              u16* __restrict__ Ubf) {
  int lin = blockIdx.x;
  int w = (lin & 7) * 72 + (lin >> 3);
  int b = w / 18, rem = w % 18;
  int m0 = (rem / 3) * 128, n0 = (rem % 3) * 128;
  __shared__ u16 As[2][128][32];
  __shared__ u16 Bs[2][128][32];
  int t = threadIdx.x, wid = t >> 6, lane = t & 63;
  int srow = wid * 32 + (lane >> 2), scol = (lane & 3) * 8;
  int wm = (wid & 1) * 64, wn = (wid >> 1) * 64;
  int r = lane & 15, quad = lane >> 4, q8 = quad * 8;
  const u16* gA = wbf + (size_t)(m0 + srow) * 384 + scol;
  const u16* gB = Gb + (size_t)b * 147456 + (size_t)(n0 + srow) * 384 + scol;

  floatx4 acc[4][4] = {};
  for (int k0 = 0; k0 < 384; k0 += 64) {
#pragma unroll
    for (int ks = 0; ks < 2; ks++) {
      gload16(gA + k0 + ks * 32,            &As[ks][wid * 32][0]);
      gload16(gA + k0 + ks * 32 + 16 * 384, &As[ks][wid * 32 + 16][0]);
      gload16(gB + k0 + ks * 32,            &Bs[ks][wid * 32][0]);
      gload16(gB + k0 + ks * 32 + 16 * 384, &Bs[ks][wid * 32 + 16][0]);
    }
    __syncthreads();
#pragma unroll
    for (int ks = 0; ks < 2; ks++) {
      bf16x8 af[4], bf[4];
#pragma unroll
      for (int i = 0; i < 4; i++) af[i] = *(const bf16x8*)(&As[ks][wm + i * 16 + r][q8]);
#pragma unroll
      for (int j = 0; j < 4; j++) bf[j] = *(const bf16x8*)(&Bs[ks][wn + j * 16 + r][q8]);
#pragma unroll
      for (int i = 0; i < 4; i++)
#pragma unroll
        for (int j = 0; j < 4; j++)
          acc[i][j] = __builtin_amdgcn_mfma_f32_16x16x32_bf16(af[i], bf[j], acc[i][j], 0, 0, 0);
    }
    __syncthreads();
  }
  u16* Ub = Ubf + (size_t)b * 294912;
#pragma unroll
  for (int i = 0; i < 4; i++)
#pragma unroll
    for (int j = 0; j < 4; j++)
#pragma unroll
      for (int v = 0; v < 4; v++) {
        int rr = m0 + wm + i * 16 + quad * 4 + v;
        int cc = n0 + wn + j * 16 + r;
        Ub[(size_t)rr * 384 + cc] = f2b(acc[i][j][v]);
      }
}

// ---------------- mid2: per bh: S, ssq (MFMA diag), softmax, M = A Wv -------
// Writes MT[b][j][e] bf16 (transposed M for mid3's B-operand).
__global__ __launch_bounds__(256) void k_mid2(const u16* __restrict__ Ubf,
                                              const u16* __restrict__ wbf,
                                              const u16* __restrict__ wvT,
                                              const float* __restrict__ temp,
                                              u16* __restrict__ MT) {
  int bh = blockIdx.x, b = bh >> 3, h = bh & 7;
  __shared__ __align__(16) u16 sUq[48][32], sUk[48][32], sWq[48][32], sWk[48][32];
  __shared__ __align__(16) u16 sA[48][72];
  __shared__ float sSsq[96];
  __shared__ float sInv[96];
  int t = threadIdx.x, wid = t >> 6, lane = t & 63;
  int r = lane & 15, quad = lane >> 4, q8 = quad * 8;
  const u16* Uq = Ubf + (size_t)b * 294912 + (size_t)(h * C_) * 384;
  const u16* Uk = Ubf + (size_t)b * 294912 + (size_t)(D_ + h * C_) * 384;
  const u16* Wq = wbf + (size_t)(h * C_) * 384;
  const u16* Wk = wbf + (size_t)(D_ + h * C_) * 384;

  floatx4 accS[3] = {};
  floatx4 accD[6] = {};
  for (int k0 = 0; k0 < 384; k0 += 32) {
    for (int idx = t; idx < 768; idx += 256) {
      int tile = idx / 192, rem = idx - tile * 192;
      int rr = rem >> 2, c8 = (rem & 3) * 8;
      const u16* src = (tile == 0 ? Uq : tile == 1 ? Uk : tile == 2 ? Wq : Wk)
                       + (size_t)rr * 384 + k0 + c8;
      u16* dst = (tile == 0 ? &sUq[rr][c8] : tile == 1 ? &sUk[rr][c8]
                  : tile == 2 ? &sWq[rr][c8] : &sWk[rr][c8]);
      *(int4*)dst = *(const int4*)src;
    }
    __syncthreads();
    if (wid < 3) {
      bf16x8 uq = *(const bf16x8*)(&sUq[wid * 16 + r][q8]);
#pragma unroll
      for (int j = 0; j < 3; j++) {
        bf16x8 wk = *(const bf16x8*)(&sWk[j * 16 + r][q8]);
        accS[j] = __builtin_amdgcn_mfma_f32_16x16x32_bf16(uq, wk, accS[j], 0, 0, 0);
      }
    } else {
#pragma unroll
      for (int i = 0; i < 3; i++) {
        bf16x8 uq = *(const bf16x8*)(&sUq[i * 16 + r][q8]);
        bf16x8 wq = *(const bf16x8*)(&sWq[i * 16 + r][q8]);
        bf16x8 uk = *(const bf16x8*)(&sUk[i * 16 + r][q8]);
        bf16x8 wk = *(const bf16x8*)(&sWk[i * 16 + r][q8]);
        accD[i]     = __builtin_amdgcn_mfma_f32_16x16x32_bf16(uq, wq, accD[i], 0, 0, 0);
        accD[3 + i] = __builtin_amdgcn_mfma_f32_16x16x32_bf16(uk, wk, accD[3 + i], 0, 0, 0);
      }
    }
    __syncthreads();
  }
  if (wid == 3) {
#pragma unroll
    for (int i = 0; i < 3; i++)
#pragma unroll
      for (int v = 0; v < 4; v++)
        if (r == quad * 4 + v) {
          sSsq[i * 16 + r] = accD[i][v];
          sSsq[48 + i * 16 + r] = accD[3 + i][v];
        }
  }
  __syncthreads();
  if (t < 96) sInv[t] = 1.f / fmaxf(sqrtf(sSsq[t]), 1e-12f);
  __syncthreads();
  // zero-pad sA cols 48..63
  for (int idx = t; idx < 48 * 16; idx += 256) sA[idx >> 4][48 + (idx & 15)] = 0;
  float T = temp[h];
  if (wid < 3) {
    float L[3][4];
    int c_base = wid * 16 + quad * 4;
#pragma unroll
    for (int j = 0; j < 3; j++)
#pragma unroll
      for (int v = 0; v < 4; v++)
        L[j][v] = accS[j][v] * sInv[c_base + v] * sInv[48 + j * 16 + r] * T;
    float mx[4], sum[4];
#pragma unroll
    for (int v = 0; v < 4; v++) mx[v] = fmaxf(fmaxf(L[0][v], L[1][v]), L[2][v]);
#pragma unroll
    for (int m = 1; m <= 8; m <<= 1)
#pragma unroll
      for (int v = 0; v < 4; v++) mx[v] = fmaxf(mx[v], __shfl_xor(mx[v], m));
#pragma unroll
    for (int v = 0; v < 4; v++) sum[v] = 0.f;
#pragma unroll
    for (int j = 0; j < 3; j++)
#pragma unroll
      for (int v = 0; v < 4; v++) { L[j][v] = __expf(L[j][v] - mx[v]); sum[v] += L[j][v]; }
#pragma unroll
    for (int m = 1; m <= 8; m <<= 1)
#pragma unroll
      for (int v = 0; v < 4; v++) sum[v] += __shfl_xor(sum[v], m);
#pragma unroll
    for (int j = 0; j < 3; j++)
#pragma unroll
      for (int v = 0; v < 4; v++)
        sA[c_base + v][j * 16 + r] = f2b(L[j][v] / sum[v]);
  }
  __syncthreads();
  // M[c][j] = sum_d A[c][d] WvT[j][d], K=64 (d padded). Output MT[j][e].
  const u16* WvTh = wvT + (size_t)h * 24576;
  floatx4 accM[3][6] = {};
#pragma unroll
  for (int ks = 0; ks < 2; ks++) {
    bf16x8 af[3];
#pragma unroll
    for (int i = 0; i < 3; i++) af[i] = *(const bf16x8*)(&sA[i * 16 + r][ks * 32 + q8]);
#pragma unroll
    for (int jj = 0; jj < 6; jj++) {
      int j = wid * 96 + jj * 16 + r;
      bf16x8 bb = *(const bf16x8*)(WvTh + (size_t)j * 64 + ks * 32 + q8);
#pragma unroll
      for (int i = 0; i < 3; i++)
        accM[i][jj] = __builtin_amdgcn_mfma_f32_16x16x32_bf16(af[i], bb, accM[i][jj], 0, 0, 0);
    }
  }
  u16* MTb = MT + (size_t)b * 147456;
#pragma unroll
  for (int i = 0; i < 3; i++)
#pragma unroll
    for (int jj = 0; jj < 6; jj++)
#pragma unroll
      for (int v = 0; v < 4; v++) {
        int c = i * 16 + quad * 4 + v;
        int j = wid * 96 + jj * 16 + r;
        MTb[(size_t)j * 384 + h * C_ + c] = f2b(accM[i][jj][v]);
      }
}

// ---------------- mid3: R[b][f][j] = sum_e P[f][e] MT[b][j][e], bf16 out ----
// grid (9 tile-combos, 32 b).
__global__ __launch_bounds__(256) void k_mid3(const u16* __restrict__ pwbf,
                                              const u16* __restrict__ MT,
                                              u16* __restrict__ R) {
  int m0 = (blockIdx.x % 3) * 128, n0 = (blockIdx.x / 3) * 128, b = blockIdx.y;
  __shared__ u16 As[2][128][32];
  __shared__ u16 Bs[2][128][32];
  int t = threadIdx.x, wid = t >> 6, lane = t & 63;
  int srow = wid * 32 + (lane >> 2), scol = (lane & 3) * 8;
  int wm = (wid & 1) * 64, wn = (wid >> 1) * 64;
  int r = lane & 15, quad = lane >> 4, q8 = quad * 8;
  const u16* gA = pwbf + (size_t)(m0 + srow) * 384 + scol;
  const u16* gB = MT + (size_t)b * 147456 + (size_t)(n0 + srow) * 384 + scol;

  floatx4 acc[4][4] = {};
  for (int k0 = 0; k0 < 384; k0 += 64) {
#pragma unroll
    for (int ks = 0; ks < 2; ks++) {
      gload16(gA + k0 + ks * 32,            &As[ks][wid * 32][0]);
      gload16(gA + k0 + ks * 32 + 16 * 384, &As[ks][wid * 32 + 16][0]);
      gload16(gB + k0 + ks * 32,            &Bs[ks][wid * 32][0]);
      gload16(gB + k0 + ks * 32 + 16 * 384, &Bs[ks][wid * 32 + 16][0]);
    }
    __syncthreads();
#pragma unroll
    for (int ks = 0; ks < 2; ks++) {
      bf16x8 af[4], bf[4];
#pragma unroll
      for (int i = 0; i < 4; i++) af[i] = *(const bf16x8*)(&As[ks][wm + i * 16 + r][q8]);
#pragma unroll
      for (int j = 0; j < 4; j++) bf[j] = *(const bf16x8*)(&Bs[ks][wn + j * 16 + r][q8]);
#pragma unroll
      for (int i = 0; i < 4; i++)
#pragma unroll
        for (int j = 0; j < 4; j++)
          acc[i][j] = __builtin_amdgcn_mfma_f32_16x16x32_bf16(af[i], bf[j], acc[i][j], 0, 0, 0);
    }
    __syncthreads();
  }
  u16* Rb = R + (size_t)b * 147456;
#pragma unroll
  for (int i = 0; i < 4; i++)
#pragma unroll
    for (int j = 0; j < 4; j++)
#pragma unroll
      for (int v = 0; v < 4; v++) {
        int rr = m0 + wm + i * 16 + quad * 4 + v;
        int cc = n0 + wn + j * 16 + r;
        Rb[(size_t)rr * 384 + cc] = f2b(acc[i][j][v]);
      }
}

// ---------------- final: Y[g][f] = sum_j xbf[g][j] R_b[f][j] + bias[f] ------
// 128x128 m97 tile; grid 2400 = (25 gt x 3 ft x 32 b), XCD swizzle 8x300.
// Tail g-tile (gt=24): A-reads overrun into xT (in-bounds ws, garbage),
// C-writes guarded by gt*128+rr < N_.
__global__ __launch_bounds__(256) void k_final(const u16* __restrict__ xbf,
                                               const u16* __restrict__ R,
                                               const float* __restrict__ bias,
                                               float* __restrict__ Y) {
  int lin = blockIdx.x;
  int w = (lin & 7) * 300 + (lin >> 3);
  int ft = w % 3, rest = w / 3;
  int b = rest / 25, gt = rest % 25;
  size_t g0 = (size_t)b * N_ + gt * 128;
  int f0 = ft * 128;
  __shared__ u16 As[2][128][32];
  __shared__ u16 Bs[2][128][32];
  int t = threadIdx.x, wid = t >> 6, lane = t & 63;
  int srow = wid * 32 + (lane >> 2), scol = (lane & 3) * 8;
  int wm = (wid & 1) * 64, wn = (wid >> 1) * 64;
  int r = lane & 15, quad = lane >> 4, q8 = quad * 8;
  const u16* gA = xbf + (g0 + srow) * 384 + scol;
  const u16* gB = R + (size_t)b * 147456 + (size_t)(f0 + srow) * 384 + scol;

  floatx4 acc[4][4] = {};
  for (int k0 = 0; k0 < 384; k0 += 64) {
#pragma unroll
    for (int ks = 0; ks < 2; ks++) {
      gload16(gA + k0 + ks * 32,            &As[ks][wid * 32][0]);
      gload16(gA + k0 + ks * 32 + 16 * 384, &As[ks][wid * 32 + 16][0]);
      gload16(gB + k0 + ks * 32,            &Bs[ks][wid * 32][0]);
      gload16(gB + k0 + ks * 32 + 16 * 384, &Bs[ks][wid * 32 + 16][0]);
    }
    __syncthreads();
#pragma unroll
    for (int ks = 0; ks < 2; ks++) {
      bf16x8 af[4], bf[4];
#pragma unroll
      for (int i = 0; i < 4; i++) af[i] = *(const bf16x8*)(&As[ks][wm + i * 16 + r][q8]);
#pragma unroll
      for (int j = 0; j < 4; j++) bf[j] = *(const bf16x8*)(&Bs[ks][wn + j * 16 + r][q8]);
#pragma unroll
      for (int i = 0; i < 4; i++)
#pragma unroll
        for (int j = 0; j < 4; j++)
          acc[i][j] = __builtin_amdgcn_mfma_f32_16x16x32_bf16(af[i], bf[j], acc[i][j], 0, 0, 0);
    }
    __syncthreads();
  }
#pragma unroll
  for (int i = 0; i < 4; i++)
#pragma unroll
    for (int j = 0; j < 4; j++) {
      int cc = f0 + wn + j * 16 + r;
      float bv = bias[cc];
#pragma unroll
      for (int v = 0; v < 4; v++) {
        int rr = wm + i * 16 + quad * 4 + v;
        if (gt * 128 + rr < N_)
          Y[(g0 + rr) * 384 + cc] = acc[i][j][v] + bv;
      }
    }
}

extern "C" void kernel_launch(void* const* d_in, const int* in_sizes, int n_in,
                              void* d_out, int out_size, void* d_ws, size_t ws_size,
                              hipStream_t stream) {
  const float* x      = (const float*)d_in[0];   // 32*3136*384
  const float* qkv_w  = (const float*)d_in[1];   // 1152*384
  const float* temp   = (const float*)d_in[2];   // 8
  const float* proj_w = (const float*)d_in[3];   // 384*384
  const float* proj_b = (const float*)d_in[4];   // 384
  float* out = (float*)d_out;

  // workspace layout (bytes)
  char* ws = (char*)d_ws;
  u16*   xbf  = (u16*)(ws);                     //  77,070,336  [g][d]
  u16*   xT   = (u16*)(ws + 77070336);          //  77,070,336  [d][g]
  u16*   wbf  = (u16*)(ws + 154140672);         //     884,736  [e][d]
  u16*   pwbf = (u16*)(ws + 155025408);         //     294,912  [f][e]
  u16*   wvT  = (u16*)(ws + 155320320);         //     393,216  [h][384][64]
  float* G    = (float*)(ws + 155713536);       //  25,165,824  [2][b][6][128][128]
  u16*   Gbf  = (u16*)(ws + 180879360);         //   9,437,184  [b][384][384]
  u16*   Ubf  = (u16*)(ws + 190316544);         //  18,874,368  [b][768][384] bf16
  u16*   MT   = (u16*)(ws + 209190912);         //   9,437,184  [b][j][e]
  u16*   R    = (u16*)(ws + 218628096);         //   9,437,184  [b][f][j]

  k_entry<<<9992, 256, 0, stream>>>(x, qkv_w, proj_w, xbf, xT, wbf, pwbf, wvT);
  k_gram<<<384, 256, 0, stream>>>(xT, G);
  k_gsum<<<768, 256, 0, stream>>>(G, Gbf);
  k_mid1<<<576, 256, 0, stream>>>(wbf, Gbf, Ubf);
  k_mid2<<<256, 256, 0, stream>>>(Ubf, wbf, wvT, temp, MT);
  k_mid3<<<dim3(9, 32), 256, 0, stream>>>(pwbf, MT, R);
  k_final<<<2400, 256, 0, stream>>>(xbf, R, proj_b, out);
}

// Round 7
// 486.092 us; speedup vs baseline: 1.2207x; 1.0017x over previous
//
#include <hip/hip_runtime.h>

// XCA: cross-covariance attention, B=32 N=3136 D=384 H=8 C=48.
// Round 8: Gram-factored pipeline.
//   - k_entry grid reordered d-major: consecutive blocks share a d-tile and
//     walk n -> xT writes + x reads form sequential DRAM streams.
//   - gram split-4 (768 blocks = 3 blocks/CU) to hide the per-K-step barrier
//     drain under co-resident blocks; plain f32 partial stores; gsum sums 4.
//   - rest unchanged from round 7 (symmetry gram, bf16 U, 128^2 final).

typedef __bf16 bf16x8 __attribute__((ext_vector_type(8)));
typedef float floatx4 __attribute__((ext_vector_type(4)));
typedef unsigned short u16;

#define B_ 32
#define N_ 3136
#define D_ 384
#define H_ 8
#define C_ 48
#define BN_ 100352   // B_*N_

__device__ __forceinline__ u16 f2b(float f) {
  unsigned u = __builtin_bit_cast(unsigned, f);
  u += 0x7FFFu + ((u >> 16) & 1u);   // RNE
  return (u16)(u >> 16);
}
__device__ __forceinline__ void gload16(const u16* g, u16* l) {
  __builtin_amdgcn_global_load_lds(
      (const __attribute__((address_space(1))) void*)g,
      (__attribute__((address_space(3))) void*)l, 16, 0, 0);
}

// ---------------- entry: cvt+transpose (blocks 0..9407) + weight prep -------
// cvt_t: x -> xbf [g][d], xT [d][g]; prep: wbf, pwbf, wvT.
// d-MAJOR order: rem/49 = d-tile, rem%49 = n-tile (write streaming).
__global__ __launch_bounds__(256) void k_entry(const float* __restrict__ x,
                                               const float* __restrict__ qkv_w,
                                               const float* __restrict__ proj_w,
                                               u16* __restrict__ xbf,
                                               u16* __restrict__ xT,
                                               u16* __restrict__ wbf,
                                               u16* __restrict__ pwbf,
                                               u16* __restrict__ wvT) {
  int lin = blockIdx.x, t = threadIdx.x;
  if (lin < 9408) {
    int b = lin / 294, rem = lin % 294;
    int d0 = (rem / 49) * 64, n0 = (rem % 49) * 64;
    const float* xp = x + ((size_t)b * N_ + n0) * D_ + d0;
    __shared__ u16 L[64][68];
    int nl = t >> 4, dl = (t & 15) * 4;
#pragma unroll
    for (int p = 0; p < 4; p++) {
      int n = nl + p * 16;
      float4 v = *(const float4*)(xp + (size_t)n * D_ + dl);
      ushort4 o;
      o.x = f2b(v.x); o.y = f2b(v.y); o.z = f2b(v.z); o.w = f2b(v.w);
      *(ushort4*)(xbf + ((size_t)(b * N_ + n0 + n)) * D_ + d0 + dl) = o;
      *(ushort4*)(&L[n][dl]) = o;
    }
    __syncthreads();
    int dl2 = t >> 4, nl2 = (t & 15) * 4;
#pragma unroll
    for (int p = 0; p < 4; p++) {
      int d = dl2 + p * 16;
      ushort4 o;
      o.x = L[nl2 + 0][d]; o.y = L[nl2 + 1][d];
      o.z = L[nl2 + 2][d]; o.w = L[nl2 + 3][d];
      *(ushort4*)(xT + (size_t)(d0 + d) * BN_ + b * N_ + n0 + nl2) = o;
    }
  } else {
    int blk = lin - 9408;
    if (blk < 432) {
      int i = blk * 256 + t;
      float4 v = ((const float4*)qkv_w)[i];
      ushort4 o;
      o.x = f2b(v.x); o.y = f2b(v.y); o.z = f2b(v.z); o.w = f2b(v.w);
      ((ushort4*)wbf)[i] = o;
    } else if (blk < 576) {
      int i = (blk - 432) * 256 + t;
      float4 v = ((const float4*)proj_w)[i];
      ushort4 o;
      o.x = f2b(v.x); o.y = f2b(v.y); o.z = f2b(v.z); o.w = f2b(v.w);
      ((ushort4*)pwbf)[i] = o;
    } else {
      int h = blk - 576;
      for (int idx = t; idx < 384 * 64; idx += 256) {
        int j = idx >> 6, d = idx & 63;
        float v = (d < 48) ? qkv_w[(size_t)(2 * D_ + h * C_ + d) * D_ + j] : 0.f;
        wvT[(size_t)h * 24576 + idx] = f2b(v);
      }
    }
  }
}

// ---------------- gram: 6 upper-tri tiles, split-4, plain f32 stores --------
// grid 768 1D; XCD swizzle 8x96. Partials [split][b][t6][128][128] f32.
// Splits: 768/768/768/832 tokens (all multiples of BK=64).
__constant__ int c_ti[6] = {0, 0, 0, 1, 1, 2};
__constant__ int c_tj[6] = {0, 1, 2, 1, 2, 2};

__global__ __launch_bounds__(256) void k_gram(const u16* __restrict__ xT,
                                              float* __restrict__ G) {
  int lin = blockIdx.x;
  int w = (lin & 7) * 96 + (lin >> 3);
  int b = w / 24, rem = w % 24;
  int split = rem / 6, t6 = rem % 6;
  int m0 = c_ti[t6] * 128, n0 = c_tj[t6] * 128;
  int kbeg = split * 768, klen = (split == 3) ? 832 : 768;
  __shared__ u16 As[2][128][32];
  __shared__ u16 Bs[2][128][32];
  int t = threadIdx.x, wid = t >> 6, lane = t & 63;
  int srow = wid * 32 + (lane >> 2), scol = (lane & 3) * 8;
  int wm = (wid & 1) * 64, wn = (wid >> 1) * 64;
  int r = lane & 15, quad = lane >> 4, q8 = quad * 8;
  const u16* base = xT + (size_t)b * N_ + kbeg + scol;
  const u16* gA = base + (size_t)(m0 + srow) * BN_;
  const u16* gB = base + (size_t)(n0 + srow) * BN_;

  floatx4 acc[4][4] = {};
  for (int k0 = 0; k0 < klen; k0 += 64) {
#pragma unroll
    for (int ks = 0; ks < 2; ks++) {
      gload16(gA + k0 + ks * 32,                     &As[ks][wid * 32][0]);
      gload16(gA + k0 + ks * 32 + (size_t)16 * BN_,  &As[ks][wid * 32 + 16][0]);
      gload16(gB + k0 + ks * 32,                     &Bs[ks][wid * 32][0]);
      gload16(gB + k0 + ks * 32 + (size_t)16 * BN_,  &Bs[ks][wid * 32 + 16][0]);
    }
    __syncthreads();
#pragma unroll
    for (int ks = 0; ks < 2; ks++) {
      bf16x8 af[4], bf[4];
#pragma unroll
      for (int i = 0; i < 4; i++) af[i] = *(const bf16x8*)(&As[ks][wm + i * 16 + r][q8]);
#pragma unroll
      for (int j = 0; j < 4; j++) bf[j] = *(const bf16x8*)(&Bs[ks][wn + j * 16 + r][q8]);
#pragma unroll
      for (int i = 0; i < 4; i++)
#pragma unroll
        for (int j = 0; j < 4; j++)
          acc[i][j] = __builtin_amdgcn_mfma_f32_16x16x32_bf16(af[i], bf[j], acc[i][j], 0, 0, 0);
    }
    __syncthreads();
  }
  float* Gp = G + ((size_t)split * 192 + b * 6 + t6) * 16384;
#pragma unroll
  for (int i = 0; i < 4; i++)
#pragma unroll
    for (int j = 0; j < 4; j++)
#pragma unroll
      for (int v = 0; v < 4; v++) {
        int rr = wm + i * 16 + quad * 4 + v;
        int cc = wn + j * 16 + r;
        Gp[(size_t)rr * 128 + cc] = acc[i][j][v];
      }
}

// ---------------- gsum: Gbf = cvt(G0+G1+G2+G3), mirrored into 384x384 -------
// grid 768: 4 parts per (b,t6). Off-diag tiles also scatter the transpose.
__global__ __launch_bounds__(256) void k_gsum(const float* __restrict__ G,
                                              u16* __restrict__ Gbf) {
  int gid = blockIdx.x, t = threadIdx.x;
  int tb = gid >> 2, part = gid & 3;
  int b = tb / 6, t6 = tb % 6;
  int ti = c_ti[t6], tj = c_tj[t6];
  const float* G0 = G + ((size_t)b * 6 + t6) * 16384;
  u16* Gb = Gbf + (size_t)b * 147456;
#pragma unroll
  for (int it = 0; it < 4; it++) {
    int idx = part * 1024 + it * 256 + t;        // float4 index in tile
    int i = idx >> 5, j4 = (idx & 31) * 4;
    float4 a = ((const float4*)G0)[idx];
    float4 c = ((const float4*)(G0 + (size_t)192 * 16384))[idx];
    float4 d = ((const float4*)(G0 + (size_t)384 * 16384))[idx];
    float4 e = ((const float4*)(G0 + (size_t)576 * 16384))[idx];
    float s0 = (a.x + c.x) + (d.x + e.x);
    float s1 = (a.y + c.y) + (d.y + e.y);
    float s2 = (a.z + c.z) + (d.z + e.z);
    float s3 = (a.w + c.w) + (d.w + e.w);
    ushort4 o;
    o.x = f2b(s0); o.y = f2b(s1); o.z = f2b(s2); o.w = f2b(s3);
    *(ushort4*)(Gb + (size_t)(ti * 128 + i) * 384 + tj * 128 + j4) = o;
    if (ti != tj) {
      int cbase = ti * 128 + i;
      Gb[(size_t)(tj * 128 + j4 + 0) * 384 + cbase] = o.x;
      Gb[(size_t)(tj * 128 + j4 + 1) * 384 + cbase] = o.y;
      Gb[(size_t)(tj * 128 + j4 + 2) * 384 + cbase] = o.z;
      Gb[(size_t)(tj * 128 + j4 + 3) * 384 + cbase] = o.w;
    }
  }
}

// ---------------- mid1: U[b][e][j] = sum_i Wqk[e][i] G[b][j][i], bf16 out ---
// grid 576 1D, XCD swizzle 8x72.
__global__ __launch_bounds__(256) void k_mid1(const u16* __restrict__ wbf,
                                              const u16* __restrict__ Gb,
                                              u16* __restrict__ Ubf) {
  int lin = blockIdx.x;
  int w = (lin & 7) * 72 + (lin >> 3);
  int b = w / 18, rem = w % 18;
  int m0 = (rem / 3) * 128, n0 = (rem % 3) * 128;
  __shared__ u16 As[2][128][32];
  __shared__ u16 Bs[2][128][32];
  int t = threadIdx.x, wid = t >> 6, lane = t & 63;
  int srow = wid * 32 + (lane >> 2), scol = (lane & 3) * 8;
  int wm = (wid & 1) * 64, wn = (wid >> 1) * 64;
  int r = lane & 15, quad = lane >> 4, q8 = quad * 8;
  const u16* gA = wbf + (size_t)(m0 + srow) * 384 + scol;
  const u16* gB = Gb + (size_t)b * 147456 + (size_t)(n0 + srow) * 384 + scol;

  floatx4 acc[4][4] = {};
  for (int k0 = 0; k0 < 384; k0 += 64) {
#pragma unroll
    for (int ks = 0; ks < 2; ks++) {
      gload16(gA + k0 + ks * 32,            &As[ks][wid * 32][0]);
      gload16(gA + k0 + ks * 32 + 16 * 384, &As[ks][wid * 32 + 16][0]);
      gload16(gB + k0 + ks * 32,            &Bs[ks][wid * 32][0]);
      gload16(gB + k0 + ks * 32 + 16 * 384, &Bs[ks][wid * 32 + 16][0]);
    }
    __syncthreads();
#pragma unroll
    for (int ks = 0; ks < 2; ks++) {
      bf16x8 af[4], bf[4];
#pragma unroll
      for (int i = 0; i < 4; i++) af[i] = *(const bf16x8*)(&As[ks][wm + i * 16 + r][q8]);
#pragma unroll
      for (int j = 0; j < 4; j++) bf[j] = *(const bf16x8*)(&Bs[ks][wn + j * 16 + r][q8]);
#pragma unroll
      for (int i = 0; i < 4; i++)
#pragma unroll
        for (int j = 0; j < 4; j++)
          acc[i][j] = __builtin_amdgcn_mfma_f32_16x16x32_bf16(af[i], bf[j], acc[i][j], 0, 0, 0);
    }
    __syncthreads();
  }
  u16* Ub = Ubf + (size_t)b * 294912;
#pragma unroll
  for (int i = 0; i < 4; i++)
#pragma unroll
    for (int j = 0; j < 4; j++)
#pragma unroll
      for (int v = 0; v < 4; v++) {
        int rr = m0 + wm + i * 16 + quad * 4 + v;
        int cc = n0 + wn + j * 16 + r;
        Ub[(size_t)rr * 384 + cc] = f2b(acc[i][j][v]);
      }
}

// ---------------- mid2: per bh: S, ssq (MFMA diag), softmax, M = A Wv -------
// Writes MT[b][j][e] bf16 (transposed M for mid3's B-operand).
__global__ __launch_bounds__(256) void k_mid2(const u16* __restrict__ Ubf,
                                              const u16* __restrict__ wbf,
                                              const u16* __restrict__ wvT,
                                              const float* __restrict__ temp,
                                              u16* __restrict__ MT) {
  int bh = blockIdx.x, b = bh >> 3, h = bh & 7;
  __shared__ __align__(16) u16 sUq[48][32], sUk[48][32], sWq[48][32], sWk[48][32];
  __shared__ __align__(16) u16 sA[48][72];
  __shared__ float sSsq[96];
  __shared__ float sInv[96];
  int t = threadIdx.x, wid = t >> 6, lane = t & 63;
  int r = lane & 15, quad = lane >> 4, q8 = quad * 8;
  const u16* Uq = Ubf + (size_t)b * 294912 + (size_t)(h * C_) * 384;
  const u16* Uk = Ubf + (size_t)b * 294912 + (size_t)(D_ + h * C_) * 384;
  const u16* Wq = wbf + (size_t)(h * C_) * 384;
  const u16* Wk = wbf + (size_t)(D_ + h * C_) * 384;

  floatx4 accS[3] = {};
  floatx4 accD[6] = {};
  for (int k0 = 0; k0 < 384; k0 += 32) {
    for (int idx = t; idx < 768; idx += 256) {
      int tile = idx / 192, rem = idx - tile * 192;
      int rr = rem >> 2, c8 = (rem & 3) * 8;
      const u16* src = (tile == 0 ? Uq : tile == 1 ? Uk : tile == 2 ? Wq : Wk)
                       + (size_t)rr * 384 + k0 + c8;
      u16* dst = (tile == 0 ? &sUq[rr][c8] : tile == 1 ? &sUk[rr][c8]
                  : tile == 2 ? &sWq[rr][c8] : &sWk[rr][c8]);
      *(int4*)dst = *(const int4*)src;
    }
    __syncthreads();
    if (wid < 3) {
      bf16x8 uq = *(const bf16x8*)(&sUq[wid * 16 + r][q8]);
#pragma unroll
      for (int j = 0; j < 3; j++) {
        bf16x8 wk = *(const bf16x8*)(&sWk[j * 16 + r][q8]);
        accS[j] = __builtin_amdgcn_mfma_f32_16x16x32_bf16(uq, wk, accS[j], 0, 0, 0);
      }
    } else {
#pragma unroll
      for (int i = 0; i < 3; i++) {
        bf16x8 uq = *(const bf16x8*)(&sUq[i * 16 + r][q8]);
        bf16x8 wq = *(const bf16x8*)(&sWq[i * 16 + r][q8]);
        bf16x8 uk = *(const bf16x8*)(&sUk[i * 16 + r][q8]);
        bf16x8 wk = *(const bf16x8*)(&sWk[i * 16 + r][q8]);
        accD[i]     = __builtin_amdgcn_mfma_f32_16x16x32_bf16(uq, wq, accD[i], 0, 0, 0);
        accD[3 + i] = __builtin_amdgcn_mfma_f32_16x16x32_bf16(uk, wk, accD[3 + i], 0, 0, 0);
      }
    }
    __syncthreads();
  }
  if (wid == 3) {
#pragma unroll
    for (int i = 0; i < 3; i++)
#pragma unroll
      for (int v = 0; v < 4; v++)
        if (r == quad * 4 + v) {
          sSsq[i * 16 + r] = accD[i][v];
          sSsq[48 + i * 16 + r] = accD[3 + i][v];
        }
  }
  __syncthreads();
  if (t < 96) sInv[t] = 1.f / fmaxf(sqrtf(sSsq[t]), 1e-12f);
  __syncthreads();
  // zero-pad sA cols 48..63
  for (int idx = t; idx < 48 * 16; idx += 256) sA[idx >> 4][48 + (idx & 15)] = 0;
  float T = temp[h];
  if (wid < 3) {
    float L[3][4];
    int c_base = wid * 16 + quad * 4;
#pragma unroll
    for (int j = 0; j < 3; j++)
#pragma unroll
      for (int v = 0; v < 4; v++)
        L[j][v] = accS[j][v] * sInv[c_base + v] * sInv[48 + j * 16 + r] * T;
    float mx[4], sum[4];
#pragma unroll
    for (int v = 0; v < 4; v++) mx[v] = fmaxf(fmaxf(L[0][v], L[1][v]), L[2][v]);
#pragma unroll
    for (int m = 1; m <= 8; m <<= 1)
#pragma unroll
      for (int v = 0; v < 4; v++) mx[v] = fmaxf(mx[v], __shfl_xor(mx[v], m));
#pragma unroll
    for (int v = 0; v < 4; v++) sum[v] = 0.f;
#pragma unroll
    for (int j = 0; j < 3; j++)
#pragma unroll
      for (int v = 0; v < 4; v++) { L[j][v] = __expf(L[j][v] - mx[v]); sum[v] += L[j][v]; }
#pragma unroll
    for (int m = 1; m <= 8; m <<= 1)
#pragma unroll
      for (int v = 0; v < 4; v++) sum[v] += __shfl_xor(sum[v], m);
#pragma unroll
    for (int j = 0; j < 3; j++)
#pragma unroll
      for (int v = 0; v < 4; v++)
        sA[c_base + v][j * 16 + r] = f2b(L[j][v] / sum[v]);
  }
  __syncthreads();
  // M[c][j] = sum_d A[c][d] WvT[j][d], K=64 (d padded). Output MT[j][e].
  const u16* WvTh = wvT + (size_t)h * 24576;
  floatx4 accM[3][6] = {};
#pragma unroll
  for (int ks = 0; ks < 2; ks++) {
    bf16x8 af[3];
#pragma unroll
    for (int i = 0; i < 3; i++) af[i] = *(const bf16x8*)(&sA[i * 16 + r][ks * 32 + q8]);
#pragma unroll
    for (int jj = 0; jj < 6; jj++) {
      int j = wid * 96 + jj * 16 + r;
      bf16x8 bb = *(const bf16x8*)(WvTh + (size_t)j * 64 + ks * 32 + q8);
#pragma unroll
      for (int i = 0; i < 3; i++)
        accM[i][jj] = __builtin_amdgcn_mfma_f32_16x16x32_bf16(af[i], bb, accM[i][jj], 0, 0, 0);
    }
  }
  u16* MTb = MT + (size_t)b * 147456;
#pragma unroll
  for (int i = 0; i < 3; i++)
#pragma unroll
    for (int jj = 0; jj < 6; jj++)
#pragma unroll
      for (int v = 0; v < 4; v++) {
        int c = i * 16 + quad * 4 + v;
        int j = wid * 96 + jj * 16 + r;
        MTb[(size_t)j * 384 + h * C_ + c] = f2b(accM[i][jj][v]);
      }
}

// ---------------- mid3: R[b][f][j] = sum_e P[f][e] MT[b][j][e], bf16 out ----
// grid (9 tile-combos, 32 b).
__global__ __launch_bounds__(256) void k_mid3(const u16* __restrict__ pwbf,
                                              const u16* __restrict__ MT,
                                              u16* __restrict__ R) {
  int m0 = (blockIdx.x % 3) * 128, n0 = (blockIdx.x / 3) * 128, b = blockIdx.y;
  __shared__ u16 As[2][128][32];
  __shared__ u16 Bs[2][128][32];
  int t = threadIdx.x, wid = t >> 6, lane = t & 63;
  int srow = wid * 32 + (lane >> 2), scol = (lane & 3) * 8;
  int wm = (wid & 1) * 64, wn = (wid >> 1) * 64;
  int r = lane & 15, quad = lane >> 4, q8 = quad * 8;
  const u16* gA = pwbf + (size_t)(m0 + srow) * 384 + scol;
  const u16* gB = MT + (size_t)b * 147456 + (size_t)(n0 + srow) * 384 + scol;

  floatx4 acc[4][4] = {};
  for (int k0 = 0; k0 < 384; k0 += 64) {
#pragma unroll
    for (int ks = 0; ks < 2; ks++) {
      gload16(gA + k0 + ks * 32,            &As[ks][wid * 32][0]);
      gload16(gA + k0 + ks * 32 + 16 * 384, &As[ks][wid * 32 + 16][0]);
      gload16(gB + k0 + ks * 32,            &Bs[ks][wid * 32][0]);
      gload16(gB + k0 + ks * 32 + 16 * 384, &Bs[ks][wid * 32 + 16][0]);
    }
    __syncthreads();
#pragma unroll
    for (int ks = 0; ks < 2; ks++) {
      bf16x8 af[4], bf[4];
#pragma unroll
      for (int i = 0; i < 4; i++) af[i] = *(const bf16x8*)(&As[ks][wm + i * 16 + r][q8]);
#pragma unroll
      for (int j = 0; j < 4; j++) bf[j] = *(const bf16x8*)(&Bs[ks][wn + j * 16 + r][q8]);
#pragma unroll
      for (int i = 0; i < 4; i++)
#pragma unroll
        for (int j = 0; j < 4; j++)
          acc[i][j] = __builtin_amdgcn_mfma_f32_16x16x32_bf16(af[i], bf[j], acc[i][j], 0, 0, 0);
    }
    __syncthreads();
  }
  u16* Rb = R + (size_t)b * 147456;
#pragma unroll
  for (int i = 0; i < 4; i++)
#pragma unroll
    for (int j = 0; j < 4; j++)
#pragma unroll
      for (int v = 0; v < 4; v++) {
        int rr = m0 + wm + i * 16 + quad * 4 + v;
        int cc = n0 + wn + j * 16 + r;
        Rb[(size_t)rr * 384 + cc] = f2b(acc[i][j][v]);
      }
}

// ---------------- final: Y[g][f] = sum_j xbf[g][j] R_b[f][j] + bias[f] ------
// 128x128 m97 tile; grid 2400 = (25 gt x 3 ft x 32 b), XCD swizzle 8x300.
__global__ __launch_bounds__(256) void k_final(const u16* __restrict__ xbf,
                                               const u16* __restrict__ R,
                                               const float* __restrict__ bias,
                                               float* __restrict__ Y) {
  int lin = blockIdx.x;
  int w = (lin & 7) * 300 + (lin >> 3);
  int ft = w % 3, rest = w / 3;
  int b = rest / 25, gt = rest % 25;
  size_t g0 = (size_t)b * N_ + gt * 128;
  int f0 = ft * 128;
  __shared__ u16 As[2][128][32];
  __shared__ u16 Bs[2][128][32];
  int t = threadIdx.x, wid = t >> 6, lane = t & 63;
  int srow = wid * 32 + (lane >> 2), scol = (lane & 3) * 8;
  int wm = (wid & 1) * 64, wn = (wid >> 1) * 64;
  int r = lane & 15, quad = lane >> 4, q8 = quad * 8;
  const u16* gA = xbf + (g0 + srow) * 384 + scol;
  const u16* gB = R + (size_t)b * 147456 + (size_t)(f0 + srow) * 384 + scol;

  floatx4 acc[4][4] = {};
  for (int k0 = 0; k0 < 384; k0 += 64) {
#pragma unroll
    for (int ks = 0; ks < 2; ks++) {
      gload16(gA + k0 + ks * 32,            &As[ks][wid * 32][0]);
      gload16(gA + k0 + ks * 32 + 16 * 384, &As[ks][wid * 32 + 16][0]);
      gload16(gB + k0 + ks * 32,            &Bs[ks][wid * 32][0]);
      gload16(gB + k0 + ks * 32 + 16 * 384, &Bs[ks][wid * 32 + 16][0]);
    }
    __syncthreads();
#pragma unroll
    for (int ks = 0; ks < 2; ks++) {
      bf16x8 af[4], bf[4];
#pragma unroll
      for (int i = 0; i < 4; i++) af[i] = *(const bf16x8*)(&As[ks][wm + i * 16 + r][q8]);
#pragma unroll
      for (int j = 0; j < 4; j++) bf[j] = *(const bf16x8*)(&Bs[ks][wn + j * 16 + r][q8]);
#pragma unroll
      for (int i = 0; i < 4; i++)
#pragma unroll
        for (int j = 0; j < 4; j++)
          acc[i][j] = __builtin_amdgcn_mfma_f32_16x16x32_bf16(af[i], bf[j], acc[i][j], 0, 0, 0);
    }
    __syncthreads();
  }
#pragma unroll
  for (int i = 0; i < 4; i++)
#pragma unroll
    for (int j = 0; j < 4; j++) {
      int cc = f0 + wn + j * 16 + r;
      float bv = bias[cc];
#pragma unroll
      for (int v = 0; v < 4; v++) {
        int rr = wm + i * 16 + quad * 4 + v;
        if (gt * 128 + rr < N_)
          Y[(g0 + rr) * 384 + cc] = acc[i][j][v] + bv;
      }
    }
}

extern "C" void kernel_launch(void* const* d_in, const int* in_sizes, int n_in,
                              void* d_out, int out_size, void* d_ws, size_t ws_size,
                              hipStream_t stream) {
  const float* x      = (const float*)d_in[0];   // 32*3136*384
  const float* qkv_w  = (const float*)d_in[1];   // 1152*384
  const float* temp   = (const float*)d_in[2];   // 8
  const float* proj_w = (const float*)d_in[3];   // 384*384
  const float* proj_b = (const float*)d_in[4];   // 384
  float* out = (float*)d_out;

  // workspace layout (bytes)
  char* ws = (char*)d_ws;
  u16*   xbf  = (u16*)(ws);                     //  77,070,336  [g][d]
  u16*   xT   = (u16*)(ws + 77070336);          //  77,070,336  [d][g]
  u16*   wbf  = (u16*)(ws + 154140672);         //     884,736  [e][d]
  u16*   pwbf = (u16*)(ws + 155025408);         //     294,912  [f][e]
  u16*   wvT  = (u16*)(ws + 155320320);         //     393,216  [h][384][64]
  float* G    = (float*)(ws + 155713536);       //  50,331,648  [4][b][6][128][128]
  u16*   Gbf  = (u16*)(ws + 206045184);         //   9,437,184  [b][384][384]
  u16*   Ubf  = (u16*)(ws + 215482368);         //  18,874,368  [b][768][384] bf16
  u16*   MT   = (u16*)(ws + 234356736);         //   9,437,184  [b][j][e]
  u16*   R    = (u16*)(ws + 243793920);         //   9,437,184  [b][f][j]

  k_entry<<<9992, 256, 0, stream>>>(x, qkv_w, proj_w, xbf, xT, wbf, pwbf, wvT);
  k_gram<<<768, 256, 0, stream>>>(xT, G);
  k_gsum<<<768, 256, 0, stream>>>(G, Gbf);
  k_mid1<<<576, 256, 0, stream>>>(wbf, Gbf, Ubf);
  k_mid2<<<256, 256, 0, stream>>>(Ubf, wbf, wvT, temp, MT);
  k_mid3<<<dim3(9, 32), 256, 0, stream>>>(pwbf, MT, R);
  k_final<<<2400, 256, 0, stream>>>(xbf, R, proj_b, out);
}

// Round 9
// 475.512 us; speedup vs baseline: 1.2479x; 1.0222x over previous
//
#include <hip/hip_runtime.h>

// XCA: cross-covariance attention, B=32 N=3136 D=384 H=8 C=48.
// Round 9b: write-granularity round (compile-fixed resubmit).
//   - k_cvt: pure streaming x->xbf (sequential f32->bf16) + weight prep.
//   - k_tr:  xbf->xT, 64d x 256n LDS-transpose tiles, 512B-contiguous
//            ushort8 row writes (32 lanes x 16B per d-row).
//   - k_final: LDS-staged epilogue -> float4 coalesced Y stores (512B rows).
//   - gram/gsum/mid1/mid2/mid3 unchanged (round-8 versions).

typedef __bf16 bf16x8 __attribute__((ext_vector_type(8)));
typedef float floatx4 __attribute__((ext_vector_type(4)));
typedef unsigned short u16;

#define B_ 32
#define N_ 3136
#define D_ 384
#define H_ 8
#define C_ 48
#define BN_ 100352   // B_*N_

__device__ __forceinline__ u16 f2b(float f) {
  unsigned u = __builtin_bit_cast(unsigned, f);
  u += 0x7FFFu + ((u >> 16) & 1u);   // RNE
  return (u16)(u >> 16);
}
__device__ __forceinline__ void gload16(const u16* g, u16* l) {
  __builtin_amdgcn_global_load_lds(
      (const __attribute__((address_space(1))) void*)g,
      (__attribute__((address_space(3))) void*)l, 16, 0, 0);
}

// ---------------- cvt: x -> xbf (streaming) + weight prep -------------------
// blocks 0..4703: 8 float4/thread strided (4704*256*8 = 9,633,792 float4).
// blocks 4704..5287: wbf / pwbf / wvT prep.
__global__ __launch_bounds__(256) void k_cvt(const float* __restrict__ x,
                                             const float* __restrict__ qkv_w,
                                             const float* __restrict__ proj_w,
                                             u16* __restrict__ xbf,
                                             u16* __restrict__ wbf,
                                             u16* __restrict__ pwbf,
                                             u16* __restrict__ wvT) {
  int lin = blockIdx.x, t = threadIdx.x;
  if (lin < 4704) {
    int base = lin * 256 + t;
#pragma unroll
    for (int k = 0; k < 8; k++) {
      int i = base + k * 1204224;           // 4704*256
      float4 v = ((const float4*)x)[i];
      ushort4 o;
      o.x = f2b(v.x); o.y = f2b(v.y); o.z = f2b(v.z); o.w = f2b(v.w);
      ((ushort4*)xbf)[i] = o;
    }
  } else {
    int blk = lin - 4704;
    if (blk < 432) {
      int i = blk * 256 + t;
      float4 v = ((const float4*)qkv_w)[i];
      ushort4 o;
      o.x = f2b(v.x); o.y = f2b(v.y); o.z = f2b(v.z); o.w = f2b(v.w);
      ((ushort4*)wbf)[i] = o;
    } else if (blk < 576) {
      int i = (blk - 432) * 256 + t;
      float4 v = ((const float4*)proj_w)[i];
      ushort4 o;
      o.x = f2b(v.x); o.y = f2b(v.y); o.z = f2b(v.z); o.w = f2b(v.w);
      ((ushort4*)pwbf)[i] = o;
    } else {
      int h = blk - 576;
      for (int idx = t; idx < 384 * 64; idx += 256) {
        int j = idx >> 6, d = idx & 63;
        float v = (d < 48) ? qkv_w[(size_t)(2 * D_ + h * C_ + d) * D_ + j] : 0.f;
        wvT[(size_t)h * 24576 + idx] = f2b(v);
      }
    }
  }
}

// ---------------- tr: xbf [g][d] -> xT [d][g], 64d x 256n tiles -------------
// grid 2496 = 32b x 6dt x 13nt (nt 0..11 = 256-wide, nt 12 = 64-wide tail).
// Writes: ushort8, 32 lanes x 16B = 512B contiguous per d-row (main tiles).
__global__ __launch_bounds__(256) void k_tr(const u16* __restrict__ xbf,
                                            u16* __restrict__ xT) {
  __shared__ __align__(16) u16 L[64][264];
  int lin = blockIdx.x, t = threadIdx.x;
  int b = lin / 78, rem = lin % 78;
  int dt = rem / 13, nt = rem % 13;
  int d0 = dt * 64;
  if (nt < 12) {
    int n0 = nt * 256;
    const u16* src0 = xbf + (size_t)(b * N_ + n0) * 384 + d0;
#pragma unroll
    for (int p = 0; p < 8; p++) {
      int nrow = (t >> 3) + p * 32;
      int dseg = (t & 7) * 8;
      int4 v = *(const int4*)(src0 + (size_t)nrow * 384 + dseg);
      const u16* pv = (const u16*)&v;
#pragma unroll
      for (int k = 0; k < 8; k++) L[dseg + k][nrow] = pv[k];
    }
    __syncthreads();
    u16* dst0 = xT + (size_t)d0 * BN_ + b * N_ + n0;
#pragma unroll
    for (int p = 0; p < 8; p++) {
      int d = (t >> 5) + p * 8;
      int nseg = (t & 31) * 8;
      int4 v = *(const int4*)(&L[d][nseg]);
      *(int4*)(dst0 + (size_t)d * BN_ + nseg) = v;
    }
  } else {
    int n0 = 3072;                           // 64-wide tail
    const u16* src0 = xbf + (size_t)(b * N_ + n0) * 384 + d0;
#pragma unroll
    for (int p = 0; p < 2; p++) {
      int nrow = (t >> 3) + p * 32;
      int dseg = (t & 7) * 8;
      int4 v = *(const int4*)(src0 + (size_t)nrow * 384 + dseg);
      const u16* pv = (const u16*)&v;
#pragma unroll
      for (int k = 0; k < 8; k++) L[dseg + k][nrow] = pv[k];
    }
    __syncthreads();
    u16* dst0 = xT + (size_t)d0 * BN_ + b * N_ + n0;
#pragma unroll
    for (int p = 0; p < 2; p++) {
      int d = (t >> 3) + p * 32;
      int nseg = (t & 7) * 8;
      int4 v = *(const int4*)(&L[d][nseg]);
      *(int4*)(dst0 + (size_t)d * BN_ + nseg) = v;
    }
  }
}

// ---------------- gram: 6 upper-tri tiles, split-4, plain f32 stores --------
// grid 768 1D; XCD swizzle 8x96. Partials [split][b][t6][128][128] f32.
__constant__ int c_ti[6] = {0, 0, 0, 1, 1, 2};
__constant__ int c_tj[6] = {0, 1, 2, 1, 2, 2};

__global__ __launch_bounds__(256) void k_gram(const u16* __restrict__ xT,
                                              float* __restrict__ G) {
  int lin = blockIdx.x;
  int w = (lin & 7) * 96 + (lin >> 3);
  int b = w / 24, rem = w % 24;
  int split = rem / 6, t6 = rem % 6;
  int m0 = c_ti[t6] * 128, n0 = c_tj[t6] * 128;
  int kbeg = split * 768, klen = (split == 3) ? 832 : 768;
  __shared__ u16 As[2][128][32];
  __shared__ u16 Bs[2][128][32];
  int t = threadIdx.x, wid = t >> 6, lane = t & 63;
  int srow = wid * 32 + (lane >> 2), scol = (lane & 3) * 8;
  int wm = (wid & 1) * 64, wn = (wid >> 1) * 64;
  int r = lane & 15, quad = lane >> 4, q8 = quad * 8;
  const u16* base = xT + (size_t)b * N_ + kbeg + scol;
  const u16* gA = base + (size_t)(m0 + srow) * BN_;
  const u16* gB = base + (size_t)(n0 + srow) * BN_;

  floatx4 acc[4][4] = {};
  for (int k0 = 0; k0 < klen; k0 += 64) {
#pragma unroll
    for (int ks = 0; ks < 2; ks++) {
      gload16(gA + k0 + ks * 32,                     &As[ks][wid * 32][0]);
      gload16(gA + k0 + ks * 32 + (size_t)16 * BN_,  &As[ks][wid * 32 + 16][0]);
      gload16(gB + k0 + ks * 32,                     &Bs[ks][wid * 32][0]);
      gload16(gB + k0 + ks * 32 + (size_t)16 * BN_,  &Bs[ks][wid * 32 + 16][0]);
    }
    __syncthreads();
#pragma unroll
    for (int ks = 0; ks < 2; ks++) {
      bf16x8 af[4], bf[4];
#pragma unroll
      for (int i = 0; i < 4; i++) af[i] = *(const bf16x8*)(&As[ks][wm + i * 16 + r][q8]);
#pragma unroll
      for (int j = 0; j < 4; j++) bf[j] = *(const bf16x8*)(&Bs[ks][wn + j * 16 + r][q8]);
#pragma unroll
      for (int i = 0; i < 4; i++)
#pragma unroll
        for (int j = 0; j < 4; j++)
          acc[i][j] = __builtin_amdgcn_mfma_f32_16x16x32_bf16(af[i], bf[j], acc[i][j], 0, 0, 0);
    }
    __syncthreads();
  }
  float* Gp = G + ((size_t)split * 192 + b * 6 + t6) * 16384;
#pragma unroll
  for (int i = 0; i < 4; i++)
#pragma unroll
    for (int j = 0; j < 4; j++)
#pragma unroll
      for (int v = 0; v < 4; v++) {
        int rr = wm + i * 16 + quad * 4 + v;
        int cc = wn + j * 16 + r;
        Gp[(size_t)rr * 128 + cc] = acc[i][j][v];
      }
}

// ---------------- gsum: Gbf = cvt(G0+G1+G2+G3), mirrored into 384x384 -------
__global__ __launch_bounds__(256) void k_gsum(const float* __restrict__ G,
                                              u16* __restrict__ Gbf) {
  int gid = blockIdx.x, t = threadIdx.x;
  int tb = gid >> 2, part = gid & 3;
  int b = tb / 6, t6 = tb % 6;
  int ti = c_ti[t6], tj = c_tj[t6];
  const float* G0 = G + ((size_t)b * 6 + t6) * 16384;
  u16* Gb = Gbf + (size_t)b * 147456;
#pragma unroll
  for (int it = 0; it < 4; it++) {
    int idx = part * 1024 + it * 256 + t;
    int i = idx >> 5, j4 = (idx & 31) * 4;
    float4 a = ((const float4*)G0)[idx];
    float4 c = ((const float4*)(G0 + (size_t)192 * 16384))[idx];
    float4 d = ((const float4*)(G0 + (size_t)384 * 16384))[idx];
    float4 e = ((const float4*)(G0 + (size_t)576 * 16384))[idx];
    float s0 = (a.x + c.x) + (d.x + e.x);
    float s1 = (a.y + c.y) + (d.y + e.y);
    float s2 = (a.z + c.z) + (d.z + e.z);
    float s3 = (a.w + c.w) + (d.w + e.w);
    ushort4 o;
    o.x = f2b(s0); o.y = f2b(s1); o.z = f2b(s2); o.w = f2b(s3);
    *(ushort4*)(Gb + (size_t)(ti * 128 + i) * 384 + tj * 128 + j4) = o;
    if (ti != tj) {
      int cbase = ti * 128 + i;
      Gb[(size_t)(tj * 128 + j4 + 0) * 384 + cbase] = o.x;
      Gb[(size_t)(tj * 128 + j4 + 1) * 384 + cbase] = o.y;
      Gb[(size_t)(tj * 128 + j4 + 2) * 384 + cbase] = o.z;
      Gb[(size_t)(tj * 128 + j4 + 3) * 384 + cbase] = o.w;
    }
  }
}

// ---------------- mid1: U[b][e][j] = sum_i Wqk[e][i] G[b][j][i], bf16 out ---
__global__ __launch_bounds__(256) void k_mid1(const u16* __restrict__ wbf,
                                              const u16* __restrict__ Gb,
                                              u16* __restrict__ Ubf) {
  int lin = blockIdx.x;
  int w = (lin & 7) * 72 + (lin >> 3);
  int b = w / 18, rem = w % 18;
  int m0 = (rem / 3) * 128, n0 = (rem % 3) * 128;
  __shared__ u16 As[2][128][32];
  __shared__ u16 Bs[2][128][32];
  int t = threadIdx.x, wid = t >> 6, lane = t & 63;
  int srow = wid * 32 + (lane >> 2), scol = (lane & 3) * 8;
  int wm = (wid & 1) * 64, wn = (wid >> 1) * 64;
  int r = lane & 15, quad = lane >> 4, q8 = quad * 8;
  const u16* gA = wbf + (size_t)(m0 + srow) * 384 + scol;
  const u16* gB = Gb + (size_t)b * 147456 + (size_t)(n0 + srow) * 384 + scol;

  floatx4 acc[4][4] = {};
  for (int k0 = 0; k0 < 384; k0 += 64) {
#pragma unroll
    for (int ks = 0; ks < 2; ks++) {
      gload16(gA + k0 + ks * 32,            &As[ks][wid * 32][0]);
      gload16(gA + k0 + ks * 32 + 16 * 384, &As[ks][wid * 32 + 16][0]);
      gload16(gB + k0 + ks * 32,            &Bs[ks][wid * 32][0]);
      gload16(gB + k0 + ks * 32 + 16 * 384, &Bs[ks][wid * 32 + 16][0]);
    }
    __syncthreads();
#pragma unroll
    for (int ks = 0; ks < 2; ks++) {
      bf16x8 af[4], bf[4];
#pragma unroll
      for (int i = 0; i < 4; i++) af[i] = *(const bf16x8*)(&As[ks][wm + i * 16 + r][q8]);
#pragma unroll
      for (int j = 0; j < 4; j++) bf[j] = *(const bf16x8*)(&Bs[ks][wn + j * 16 + r][q8]);
#pragma unroll
      for (int i = 0; i < 4; i++)
#pragma unroll
        for (int j = 0; j < 4; j++)
          acc[i][j] = __builtin_amdgcn_mfma_f32_16x16x32_bf16(af[i], bf[j], acc[i][j], 0, 0, 0);
    }
    __syncthreads();
  }
  u16* Ub = Ubf + (size_t)b * 294912;
#pragma unroll
  for (int i = 0; i < 4; i++)
#pragma unroll
    for (int j = 0; j < 4; j++)
#pragma unroll
      for (int v = 0; v < 4; v++) {
        int rr = m0 + wm + i * 16 + quad * 4 + v;
        int cc = n0 + wn + j * 16 + r;
        Ub[(size_t)rr * 384 + cc] = f2b(acc[i][j][v]);
      }
}

// ---------------- mid2: per bh: S, ssq (MFMA diag), softmax, M = A Wv -------
__global__ __launch_bounds__(256) void k_mid2(const u16* __restrict__ Ubf,
                                              const u16* __restrict__ wbf,
                                              const u16* __restrict__ wvT,
                                              const float* __restrict__ temp,
                                              u16* __restrict__ MT) {
  int bh = blockIdx.x, b = bh >> 3, h = bh & 7;
  __shared__ __align__(16) u16 sUq[48][32], sUk[48][32], sWq[48][32], sWk[48][32];
  __shared__ __align__(16) u16 sA[48][72];
  __shared__ float sSsq[96];
  __shared__ float sInv[96];
  int t = threadIdx.x, wid = t >> 6, lane = t & 63;
  int r = lane & 15, quad = lane >> 4, q8 = quad * 8;
  const u16* Uq = Ubf + (size_t)b * 294912 + (size_t)(h * C_) * 384;
  const u16* Uk = Ubf + (size_t)b * 294912 + (size_t)(D_ + h * C_) * 384;
  const u16* Wq = wbf + (size_t)(h * C_) * 384;
  const u16* Wk = wbf + (size_t)(D_ + h * C_) * 384;

  floatx4 accS[3] = {};
  floatx4 accD[6] = {};
  for (int k0 = 0; k0 < 384; k0 += 32) {
    for (int idx = t; idx < 768; idx += 256) {
      int tile = idx / 192, rem = idx - tile * 192;
      int rr = rem >> 2, c8 = (rem & 3) * 8;
      const u16* src = (tile == 0 ? Uq : tile == 1 ? Uk : tile == 2 ? Wq : Wk)
                       + (size_t)rr * 384 + k0 + c8;
      u16* dst = (tile == 0 ? &sUq[rr][c8] : tile == 1 ? &sUk[rr][c8]
                  : tile == 2 ? &sWq[rr][c8] : &sWk[rr][c8]);
      *(int4*)dst = *(const int4*)src;
    }
    __syncthreads();
    if (wid < 3) {
      bf16x8 uq = *(const bf16x8*)(&sUq[wid * 16 + r][q8]);
#pragma unroll
      for (int j = 0; j < 3; j++) {
        bf16x8 wk = *(const bf16x8*)(&sWk[j * 16 + r][q8]);
        accS[j] = __builtin_amdgcn_mfma_f32_16x16x32_bf16(uq, wk, accS[j], 0, 0, 0);
      }
    } else {
#pragma unroll
      for (int i = 0; i < 3; i++) {
        bf16x8 uq = *(const bf16x8*)(&sUq[i * 16 + r][q8]);
        bf16x8 wq = *(const bf16x8*)(&sWq[i * 16 + r][q8]);
        bf16x8 uk = *(const bf16x8*)(&sUk[i * 16 + r][q8]);
        bf16x8 wk = *(const bf16x8*)(&sWk[i * 16 + r][q8]);
        accD[i]     = __builtin_amdgcn_mfma_f32_16x16x32_bf16(uq, wq, accD[i], 0, 0, 0);
        accD[3 + i] = __builtin_amdgcn_mfma_f32_16x16x32_bf16(uk, wk, accD[3 + i], 0, 0, 0);
      }
    }
    __syncthreads();
  }
  if (wid == 3) {
#pragma unroll
    for (int i = 0; i < 3; i++)
#pragma unroll
      for (int v = 0; v < 4; v++)
        if (r == quad * 4 + v) {
          sSsq[i * 16 + r] = accD[i][v];
          sSsq[48 + i * 16 + r] = accD[3 + i][v];
        }
  }
  __syncthreads();
  if (t < 96) sInv[t] = 1.f / fmaxf(sqrtf(sSsq[t]), 1e-12f);
  __syncthreads();
  for (int idx = t; idx < 48 * 16; idx += 256) sA[idx >> 4][48 + (idx & 15)] = 0;
  float T = temp[h];
  if (wid < 3) {
    float L[3][4];
    int c_base = wid * 16 + quad * 4;
#pragma unroll
    for (int j = 0; j < 3; j++)
#pragma unroll
      for (int v = 0; v < 4; v++)
        L[j][v] = accS[j][v] * sInv[c_base + v] * sInv[48 + j * 16 + r] * T;
    float mx[4], sum[4];
#pragma unroll
    for (int v = 0; v < 4; v++) mx[v] = fmaxf(fmaxf(L[0][v], L[1][v]), L[2][v]);
#pragma unroll
    for (int m = 1; m <= 8; m <<= 1)
#pragma unroll
      for (int v = 0; v < 4; v++) mx[v] = fmaxf(mx[v], __shfl_xor(mx[v], m));
#pragma unroll
    for (int v = 0; v < 4; v++) sum[v] = 0.f;
#pragma unroll
    for (int j = 0; j < 3; j++)
#pragma unroll
      for (int v = 0; v < 4; v++) { L[j][v] = __expf(L[j][v] - mx[v]); sum[v] += L[j][v]; }
#pragma unroll
    for (int m = 1; m <= 8; m <<= 1)
#pragma unroll
      for (int v = 0; v < 4; v++) sum[v] += __shfl_xor(sum[v], m);
#pragma unroll
    for (int j = 0; j < 3; j++)
#pragma unroll
      for (int v = 0; v < 4; v++)
        sA[c_base + v][j * 16 + r] = f2b(L[j][v] / sum[v]);
  }
  __syncthreads();
  const u16* WvTh = wvT + (size_t)h * 24576;
  floatx4 accM[3][6] = {};
#pragma unroll
  for (int ks = 0; ks < 2; ks++) {
    bf16x8 af[3];
#pragma unroll
    for (int i = 0; i < 3; i++) af[i] = *(const bf16x8*)(&sA[i * 16 + r][ks * 32 + q8]);
#pragma unroll
    for (int jj = 0; jj < 6; jj++) {
      int j = wid * 96 + jj * 16 + r;
      bf16x8 bb = *(const bf16x8*)(WvTh + (size_t)j * 64 + ks * 32 + q8);
#pragma unroll
      for (int i = 0; i < 3; i++)
        accM[i][jj] = __builtin_amdgcn_mfma_f32_16x16x32_bf16(af[i], bb, accM[i][jj], 0, 0, 0);
    }
  }
  u16* MTb = MT + (size_t)b * 147456;
#pragma unroll
  for (int i = 0; i < 3; i++)
#pragma unroll
    for (int jj = 0; jj < 6; jj++)
#pragma unroll
      for (int v = 0; v < 4; v++) {
        int c = i * 16 + quad * 4 + v;
        int j = wid * 96 + jj * 16 + r;
        MTb[(size_t)j * 384 + h * C_ + c] = f2b(accM[i][jj][v]);
      }
}

// ---------------- mid3: R[b][f][j] = sum_e P[f][e] MT[b][j][e], bf16 out ----
__global__ __launch_bounds__(256) void k_mid3(const u16* __restrict__ pwbf,
                                              const u16* __restrict__ MT,
                                              u16* __restrict__ R) {
  int m0 = (blockIdx.x % 3) * 128, n0 = (blockIdx.x / 3) * 128, b = blockIdx.y;
  __shared__ u16 As[2][128][32];
  __shared__ u16 Bs[2][128][32];
  int t = threadIdx.x, wid = t >> 6, lane = t & 63;
  int srow = wid * 32 + (lane >> 2), scol = (lane & 3) * 8;
  int wm = (wid & 1) * 64, wn = (wid >> 1) * 64;
  int r = lane & 15, quad = lane >> 4, q8 = quad * 8;
  const u16* gA = pwbf + (size_t)(m0 + srow) * 384 + scol;
  const u16* gB = MT + (size_t)b * 147456 + (size_t)(n0 + srow) * 384 + scol;

  floatx4 acc[4][4] = {};
  for (int k0 = 0; k0 < 384; k0 += 64) {
#pragma unroll
    for (int ks = 0; ks < 2; ks++) {
      gload16(gA + k0 + ks * 32,            &As[ks][wid * 32][0]);
      gload16(gA + k0 + ks * 32 + 16 * 384, &As[ks][wid * 32 + 16][0]);
      gload16(gB + k0 + ks * 32,            &Bs[ks][wid * 32][0]);
      gload16(gB + k0 + ks * 32 + 16 * 384, &Bs[ks][wid * 32 + 16][0]);
    }
    __syncthreads();
#pragma unroll
    for (int ks = 0; ks < 2; ks++) {
      bf16x8 af[4], bf[4];
#pragma unroll
      for (int i = 0; i < 4; i++) af[i] = *(const bf16x8*)(&As[ks][wm + i * 16 + r][q8]);
#pragma unroll
      for (int j = 0; j < 4; j++) bf[j] = *(const bf16x8*)(&Bs[ks][wn + j * 16 + r][q8]);
#pragma unroll
      for (int i = 0; i < 4; i++)
#pragma unroll
        for (int j = 0; j < 4; j++)
          acc[i][j] = __builtin_amdgcn_mfma_f32_16x16x32_bf16(af[i], bf[j], acc[i][j], 0, 0, 0);
    }
    __syncthreads();
  }
  u16* Rb = R + (size_t)b * 147456;
#pragma unroll
  for (int i = 0; i < 4; i++)
#pragma unroll
    for (int j = 0; j < 4; j++)
#pragma unroll
      for (int v = 0; v < 4; v++) {
        int rr = m0 + wm + i * 16 + quad * 4 + v;
        int cc = n0 + wn + j * 16 + r;
        Rb[(size_t)rr * 384 + cc] = f2b(acc[i][j][v]);
      }
}

// ---------------- final: Y[g][f] = sum_j xbf[g][j] R_b[f][j] + bias[f] ------
// 128x128 m97 tile; grid 2400, XCD swizzle 8x300. LDS-staged epilogue:
// C tile -> LDS (two 64-row halves in the 32KB As/Bs space) -> float4 stores.
__global__ __launch_bounds__(256) void k_final(const u16* __restrict__ xbf,
                                               const u16* __restrict__ R,
                                               const float* __restrict__ bias,
                                               float* __restrict__ Y) {
  int lin = blockIdx.x;
  int w = (lin & 7) * 300 + (lin >> 3);
  int ft = w % 3, rest = w / 3;
  int b = rest / 25, gt = rest % 25;
  size_t g0 = (size_t)b * N_ + gt * 128;
  int f0 = ft * 128;
  __shared__ __align__(16) u16 smem[16384];   // As(8K u16) + Bs(8K u16) = 32KB
  u16 (*As)[128][32] = (u16(*)[128][32])smem;
  u16 (*Bs)[128][32] = (u16(*)[128][32])(smem + 8192);
  int t = threadIdx.x, wid = t >> 6, lane = t & 63;
  int srow = wid * 32 + (lane >> 2), scol = (lane & 3) * 8;
  int wm = (wid & 1) * 64, wn = (wid >> 1) * 64;
  int r = lane & 15, quad = lane >> 4, q8 = quad * 8;
  const u16* gA = xbf + (g0 + srow) * 384 + scol;
  const u16* gB = R + (size_t)b * 147456 + (size_t)(f0 + srow) * 384 + scol;

  floatx4 acc[4][4] = {};
  for (int k0 = 0; k0 < 384; k0 += 64) {
#pragma unroll
    for (int ks = 0; ks < 2; ks++) {
      gload16(gA + k0 + ks * 32,            &As[ks][wid * 32][0]);
      gload16(gA + k0 + ks * 32 + 16 * 384, &As[ks][wid * 32 + 16][0]);
      gload16(gB + k0 + ks * 32,            &Bs[ks][wid * 32][0]);
      gload16(gB + k0 + ks * 32 + 16 * 384, &Bs[ks][wid * 32 + 16][0]);
    }
    __syncthreads();
#pragma unroll
    for (int ks = 0; ks < 2; ks++) {
      bf16x8 af[4], bf[4];
#pragma unroll
      for (int i = 0; i < 4; i++) af[i] = *(const bf16x8*)(&As[ks][wm + i * 16 + r][q8]);
#pragma unroll
      for (int j = 0; j < 4; j++) bf[j] = *(const bf16x8*)(&Bs[ks][wn + j * 16 + r][q8]);
#pragma unroll
      for (int i = 0; i < 4; i++)
#pragma unroll
        for (int j = 0; j < 4; j++)
          acc[i][j] = __builtin_amdgcn_mfma_f32_16x16x32_bf16(af[i], bf[j], acc[i][j], 0, 0, 0);
    }
    __syncthreads();
  }
  // epilogue: two 64-row halves staged through LDS, float4 coalesced stores
  float* Lf = (float*)smem;   // [64][128]
#pragma unroll
  for (int h = 0; h < 2; h++) {
    __syncthreads();
    if ((wid & 1) == h) {
#pragma unroll
      for (int i = 0; i < 4; i++)
#pragma unroll
        for (int j = 0; j < 4; j++) {
          int cc = wn + j * 16 + r;
          float bv = bias[f0 + cc];
#pragma unroll
          for (int v = 0; v < 4; v++)
            Lf[(i * 16 + quad * 4 + v) * 128 + cc] = acc[i][j][v] + bv;
        }
    }
    __syncthreads();
#pragma unroll
    for (int p = 0; p < 8; p++) {
      int row = (t >> 5) + p * 8;
      int grow = h * 64 + row;
      int col = (t & 31) * 4;
      if (gt * 128 + grow < N_) {
        float4 vv = *(const float4*)(&Lf[row * 128 + col]);
        *(float4*)(&Y[(g0 + grow) * 384 + f0 + col]) = vv;
      }
    }
  }
}

extern "C" void kernel_launch(void* const* d_in, const int* in_sizes, int n_in,
                              void* d_out, int out_size, void* d_ws, size_t ws_size,
                              hipStream_t stream) {
  const float* x      = (const float*)d_in[0];   // 32*3136*384
  const float* qkv_w  = (const float*)d_in[1];   // 1152*384
  const float* temp   = (const float*)d_in[2];   // 8
  const float* proj_w = (const float*)d_in[3];   // 384*384
  const float* proj_b = (const float*)d_in[4];   // 384
  float* out = (float*)d_out;

  // workspace layout (bytes)
  char* ws = (char*)d_ws;
  u16*   xbf  = (u16*)(ws);                     //  77,070,336  [g][d]
  u16*   xT   = (u16*)(ws + 77070336);          //  77,070,336  [d][g]
  u16*   wbf  = (u16*)(ws + 154140672);         //     884,736  [e][d]
  u16*   pwbf = (u16*)(ws + 155025408);         //     294,912  [f][e]
  u16*   wvT  = (u16*)(ws + 155320320);         //     393,216  [h][384][64]
  float* G    = (float*)(ws + 155713536);       //  50,331,648  [4][b][6][128][128]
  u16*   Gbf  = (u16*)(ws + 206045184);         //   9,437,184  [b][384][384]
  u16*   Ubf  = (u16*)(ws + 215482368);         //  18,874,368  [b][768][384] bf16
  u16*   MT   = (u16*)(ws + 234356736);         //   9,437,184  [b][j][e]
  u16*   R    = (u16*)(ws + 243793920);         //   9,437,184  [b][f][j]

  k_cvt<<<5288, 256, 0, stream>>>(x, qkv_w, proj_w, xbf, wbf, pwbf, wvT);
  k_tr<<<2496, 256, 0, stream>>>(xbf, xT);
  k_gram<<<768, 256, 0, stream>>>(xT, G);
  k_gsum<<<768, 256, 0, stream>>>(G, Gbf);
  k_mid1<<<576, 256, 0, stream>>>(wbf, Gbf, Ubf);
  k_mid2<<<256, 256, 0, stream>>>(Ubf, wbf, wvT, temp, MT);
  k_mid3<<<dim3(9, 32), 256, 0, stream>>>(pwbf, MT, R);
  k_final<<<2400, 256, 0, stream>>>(xbf, R, proj_b, out);
}